// Round 6
// baseline (371.327 us; speedup 1.0000x reference)
//
#include <hip/hip_runtime.h>
#include <math.h>

typedef __attribute__((ext_vector_type(8))) short short8;
typedef __attribute__((ext_vector_type(4))) float f32x4;

#define B_SZ 8192
#define D_INN 4000
#define EMBD 96
#define H0D 2048
#define H1D 1024
#define KDIM 4096  // EMB + D_IN

#define MFMA_BF16 __builtin_amdgcn_mfma_f32_16x16x32_bf16

__device__ __forceinline__ unsigned short f2bf(float f) {
  union { float f; unsigned u; } v; v.f = f;
  unsigned r = v.u + 0x7FFFu + ((v.u >> 16) & 1u);
  return (unsigned short)(r >> 16);
}
__device__ __forceinline__ float bf2f(unsigned short h) {
  union { unsigned u; float f; } v; v.u = ((unsigned)h) << 16;
  return v.f;
}
__device__ __forceinline__ void gld_lds16(const void* g, void* l) {
  __builtin_amdgcn_global_load_lds(
      (const __attribute__((address_space(1))) unsigned int*)g,
      (__attribute__((address_space(3))) unsigned int*)l, 16, 0, 0);
}

// ---- transpose + fp32->bf16 convert: out[c][r] = bf16(in[r][c]) ----
__global__ __launch_bounds__(256) void transpose_cvt(
    const float* __restrict__ in, unsigned short* __restrict__ out, int R, int C) {
  __shared__ float tile[32][33];
  int c0 = blockIdx.x * 32, r0 = blockIdx.y * 32;
  int tc = threadIdx.x & 31, tr = threadIdx.x >> 5;
#pragma unroll
  for (int i = 0; i < 4; ++i) {
    int r = tr + i * 8;
    tile[r][tc] = in[(size_t)(r0 + r) * C + (c0 + tc)];
  }
  __syncthreads();
#pragma unroll
  for (int i = 0; i < 4; ++i) {
    int rr = tr + i * 8;
    out[(size_t)(c0 + rr) * R + (r0 + tc)] = f2bf(tile[tc][rr]);
  }
}

// ---- batched transpose for We: [64][1024][32] f32 -> Wet [64][32][1024] bf16 ----
__global__ __launch_bounds__(256) void transpose_cvt_we(
    const float* __restrict__ in, unsigned short* __restrict__ out) {
  __shared__ float tile[32][33];
  const int e = blockIdx.y, r0 = blockIdx.x * 32;
  const float* src = in + (size_t)e * 32768;
  unsigned short* dst = out + (size_t)e * 32768;
  int tc = threadIdx.x & 31, tr = threadIdx.x >> 5;
#pragma unroll
  for (int i = 0; i < 4; ++i) {
    int r = tr + i * 8;
    tile[r][tc] = src[(size_t)(r0 + r) * 32 + tc];
  }
  __syncthreads();
#pragma unroll
  for (int i = 0; i < 4; ++i) {
    int rr = tr + i * 8;
    dst[(size_t)rr * H1D + r0 + tc] = f2bf(tile[tc][rr]);
  }
}

// ---- build A = [emb_gather | inputs] in bf16, vectorized 8-wide ----
__global__ __launch_bounds__(256) void build_A(
    const float* __restrict__ inputs, const float* __restrict__ emb,
    const int* __restrict__ ballot, const int* __restrict__ contest,
    unsigned short* __restrict__ A) {
  int gid = blockIdx.x * 256 + threadIdx.x;   // chunk of 8 elems
  int b = gid >> 9, c = gid & 511;            // 512 chunks per row of 4096
  const float* src;
  if (c < EMBD / 8) {
    int e = ballot[b] * 8 + contest[b];
    src = emb + (size_t)e * EMBD + c * 8;
  } else {
    src = inputs + (size_t)b * D_INN + (c - EMBD / 8) * 8;
  }
  float4 v0 = *(const float4*)src;
  float4 v1 = *(const float4*)(src + 4);
  unsigned short r[8];
  r[0] = f2bf(v0.x); r[1] = f2bf(v0.y); r[2] = f2bf(v0.z); r[3] = f2bf(v0.w);
  r[4] = f2bf(v1.x); r[5] = f2bf(v1.y); r[6] = f2bf(v1.z); r[7] = f2bf(v1.w);
  *reinterpret_cast<short8*>(A + (size_t)b * KDIM + c * 8) =
      *reinterpret_cast<const short8*>(r);
}

// ---- NT bf16 MFMA GEMM: A in LDS (dbuf, BK=64), B in REGISTERS ----
// 8 waves = 2(M) x 4(N), 512 threads, BN=256, BM=256|128.
// LDS holds only A (2 x BM x 128 B): LDS traffic/K-tile = 160 KB (~1250 cyc)
// < MFMA 2483 cyc. B fragments loaded per-wave from global per tile (JIT);
// bn = bid % NBN pins each XCD to ONE B panel (2 MB, L2-resident) so B rides
// the idle VMEM pipe. One barrier per K-tile, no mid-tile barrier: waves
// desync within the window so LDS reads overlap other waves' MFMA bursts.
// Slot-overwrite safety: stage(t+1 -> buf^1) is issued after the end-of-(t-1)
// barrier, which follows every wave's reads of buf^1 (tile t-1) retiring.
// Swizzle (verified 0-conflict): stored slot = s ^ (row&7) via pre-swizzled
// global source (linear gld_lds dest) + swizzled ds_read.
template <int BM, int K, int NBN>
__global__ __launch_bounds__(512) void gemm_nt_breg(
    const unsigned short* __restrict__ A, const unsigned short* __restrict__ Bt,
    const float* __restrict__ bias, unsigned short* __restrict__ C, int N) {
  constexpr int MREP = BM / 32;       // acc rows of 16 per wave
  constexpr int AI = BM / 64;         // gld_lds per thread per tile
  constexpr int NT = K / 64;
  constexpr int NCH = MREP / 2;       // 2-mi compute chunks
  __shared__ char lds[2 * BM * 128];

  const int tid = threadIdx.x;
  const int w = tid >> 6, l = tid & 63;
  const int lr = l & 15, kg = l >> 4;
  const int wm = w >> 2, wn = w & 3;

  const int bid = blockIdx.x;
  const int bn = bid % NBN;           // bid%8 = XCD -> one B panel per XCD
  const int bm = bid / NBN;

  // A staging source (pre-swizzled slot; LDS dest stays linear)
  const int presl = (l & 7) ^ (l >> 3);
  const unsigned short* ga[AI];
#pragma unroll
  for (int i = 0; i < AI; ++i)
    ga[i] = A + (size_t)(bm * BM + i * 64 + w * 8 + (l >> 3)) * K + presl * 8;

  // B fragment base: lane (kg,lr) covers col bn*256+wn*64+ni*16+lr, k-slot kg
  const unsigned short* gb = Bt + (size_t)(bn * 256 + wn * 64 + lr) * K + kg * 8;

  f32x4 acc[MREP][4] = {};

  auto stageA = [&](int t, int buf) {
#pragma unroll
    for (int i = 0; i < AI; ++i)
      gld_lds16(ga[i] + (size_t)t * 64,
                lds + buf * (BM * 128) + i * 8192 + w * 1024);
  };

  stageA(0, 0);
  asm volatile("s_waitcnt vmcnt(0)" ::: "memory");
  __builtin_amdgcn_s_barrier();

  for (int t = 0; t < NT; ++t) {
    const int buf = t & 1;
    // JIT B loads (VMEM pipe, L2-hit); first use ~after A reads issue
    short8 bv[8];
#pragma unroll
    for (int ni = 0; ni < 4; ++ni)
#pragma unroll
      for (int kk = 0; kk < 2; ++kk)
        bv[ni * 2 + kk] =
            *(const short8*)(gb + (size_t)ni * 16 * K + t * 64 + kk * 32);
    if (t + 1 < NT) stageA(t + 1, buf ^ 1);

    const char* pa = lds + buf * (BM * 128);
#pragma unroll
    for (int c = 0; c < NCH; ++c) {
      short8 af[2][2];
#pragma unroll
      for (int mi = 0; mi < 2; ++mi)
#pragma unroll
        for (int kk = 0; kk < 2; ++kk) {
          const int row = wm * (BM / 2) + (c * 2 + mi) * 16 + lr;
          const int slot = ((kk << 2) | kg) ^ (row & 7);
          af[mi][kk] = *(const short8*)(pa + row * 128 + slot * 16);
        }
      __builtin_amdgcn_s_setprio(1);
#pragma unroll
      for (int mi = 0; mi < 2; ++mi)
#pragma unroll
        for (int ni = 0; ni < 4; ++ni)
#pragma unroll
          for (int kk = 0; kk < 2; ++kk)
            acc[c * 2 + mi][ni] = MFMA_BF16(af[mi][kk], bv[ni * 2 + kk],
                                            acc[c * 2 + mi][ni], 0, 0, 0);
      __builtin_amdgcn_s_setprio(0);
    }
    if (t + 1 < NT) {
      asm volatile("s_waitcnt vmcnt(0)" ::: "memory");  // stage(t+1) landed
      __builtin_amdgcn_s_barrier();
    }
  }

  // epilogue: bias + relu + bf16 store.  D: col=lane&15, row=(lane>>4)*4+j
#pragma unroll
  for (int mi = 0; mi < MREP; ++mi) {
    const int row0 = bm * BM + wm * (BM / 2) + mi * 16 + kg * 4;
#pragma unroll
    for (int ni = 0; ni < 4; ++ni) {
      const int col = bn * 256 + wn * 64 + ni * 16 + lr;
      const float bv2 = bias[col];
#pragma unroll
      for (int j = 0; j < 4; ++j) {
        float v = acc[mi][ni][j] + bv2;
        v = v > 0.f ? v : 0.f;
        C[(size_t)(row0 + j) * N + col] = f2bf(v);
      }
    }
  }
}

// ---- routed expert head via MFMA: one block per expert ----
// out[s][o] = sigmoid(h1[s] . Wet[e][o] + be[e][o]) for samples s of expert e.
// Each wave: 32-sample chunk x 32 outputs x K=1024 -> 128 MFMAs. A rows
// gathered from h1 (L2), B rows contiguous from Wet (L2). ~537 MFLOP total.
__global__ __launch_bounds__(256) void expert_head_mfma(
    const unsigned short* __restrict__ h1, const unsigned short* __restrict__ Wet,
    const float* __restrict__ be, const int* __restrict__ ballot,
    const int* __restrict__ contest, float* __restrict__ out) {
  const int e = blockIdx.x;
  __shared__ unsigned short sidx[1024];
  __shared__ int scnt;
  if (threadIdx.x == 0) scnt = 0;
  __syncthreads();
  for (int i = threadIdx.x; i < B_SZ; i += 256)
    if (ballot[i] * 8 + contest[i] == e) {
      int p = atomicAdd(&scnt, 1);
      if (p < 1024) sidx[p] = (unsigned short)i;
    }
  __syncthreads();
  const int cnt = min(scnt, 1024);
  const int w = threadIdx.x >> 6, l = threadIdx.x & 63;
  const int lr = l & 15, kg = l >> 4;
  const unsigned short* wbase = Wet + (size_t)e * 32768;
  for (int c0 = w * 32; c0 < cnt; c0 += 128) {
    const int ns = min(32, cnt - c0);
    f32x4 acc[2][2] = {};
    int ridx[2];
#pragma unroll
    for (int mi = 0; mi < 2; ++mi) {
      int rr = mi * 16 + lr;
      ridx[mi] = sidx[c0 + (rr < ns ? rr : 0)];
    }
#pragma unroll 4
    for (int kk = 0; kk < 32; ++kk) {
      short8 a0 = *(const short8*)(h1 + (size_t)ridx[0] * H1D + kk * 32 + kg * 8);
      short8 a1 = *(const short8*)(h1 + (size_t)ridx[1] * H1D + kk * 32 + kg * 8);
      short8 b0 = *(const short8*)(wbase + (size_t)lr * H1D + kk * 32 + kg * 8);
      short8 b1 = *(const short8*)(wbase + (size_t)(16 + lr) * H1D + kk * 32 + kg * 8);
      acc[0][0] = MFMA_BF16(a0, b0, acc[0][0], 0, 0, 0);
      acc[0][1] = MFMA_BF16(a0, b1, acc[0][1], 0, 0, 0);
      acc[1][0] = MFMA_BF16(a1, b0, acc[1][0], 0, 0, 0);
      acc[1][1] = MFMA_BF16(a1, b1, acc[1][1], 0, 0, 0);
    }
#pragma unroll
    for (int mi = 0; mi < 2; ++mi)
#pragma unroll
      for (int ni = 0; ni < 2; ++ni)
#pragma unroll
        for (int j = 0; j < 4; ++j) {
          int row = mi * 16 + kg * 4 + j;
          int col = ni * 16 + lr;
          if (row < ns) {
            float x = acc[mi][ni][j] + be[e * 32 + col];
            out[(size_t)sidx[c0 + row] * 32 + col] = 1.f / (1.f + expf(-x));
          }
        }
  }
}

extern "C" void kernel_launch(void* const* d_in, const int* in_sizes, int n_in,
                              void* d_out, int out_size, void* d_ws, size_t ws_size,
                              hipStream_t stream) {
  const float* inputs = (const float*)d_in[0];
  const float* emb    = (const float*)d_in[1];
  const float* W0     = (const float*)d_in[2];
  const float* b0     = (const float*)d_in[3];
  const float* W1     = (const float*)d_in[4];
  const float* b1     = (const float*)d_in[5];
  const float* We     = (const float*)d_in[6];
  const float* be     = (const float*)d_in[7];
  const int* ballot   = (const int*)d_in[8];
  const int* contest  = (const int*)d_in[9];
  float* out = (float*)d_out;

  char* ws = (char*)d_ws;
  unsigned short* A   = (unsigned short*)(ws);                 //  67108864 B
  unsigned short* W0t = (unsigned short*)(ws + 67108864);      //  16777216 B
  unsigned short* h0  = (unsigned short*)(ws + 83886080);      //  33554432 B
  unsigned short* W1t = (unsigned short*)(ws + 117440512);     //   4194304 B
  unsigned short* h1  = (unsigned short*)(ws + 121634816);     //  16777216 B
  unsigned short* Wet = (unsigned short*)(ws);                 // reuses A (dead after GEMM1)

  dim3 blk(256);
  transpose_cvt<<<dim3(H0D / 32, KDIM / 32, 1), blk, 0, stream>>>(W0, W0t, KDIM, H0D);
  transpose_cvt<<<dim3(H1D / 32, H0D / 32, 1), blk, 0, stream>>>(W1, W1t, H0D, H1D);
  build_A<<<dim3(B_SZ * 512 / 256), blk, 0, stream>>>(inputs, emb, ballot, contest, A);
  // GEMM1: [8192x4096] x [2048x4096]^T, 256x256 tiles -> 32*8 = 256 blocks
  gemm_nt_breg<256, KDIM, 8><<<dim3(256), dim3(512), 0, stream>>>(A, W0t, b0, h0, H0D);
  // We transpose into the now-dead A region
  transpose_cvt_we<<<dim3(32, 64), blk, 0, stream>>>(We, Wet);
  // GEMM2: [8192x2048] x [1024x2048]^T, 128x256 tiles -> 64*4 = 256 blocks
  gemm_nt_breg<128, H0D, 4><<<dim3(256), dim3(512), 0, stream>>>(h0, W1t, b1, h1, H1D);
  // routed head: 64 blocks (one per expert), MFMA matvec
  expert_head_mfma<<<dim3(64), blk, 0, stream>>>(h1, Wet, be, ballot, contest, out);
}

// Round 7
// 243.171 us; speedup vs baseline: 1.5270x; 1.5270x over previous
//
#include <hip/hip_runtime.h>
#include <math.h>

typedef __attribute__((ext_vector_type(8))) short short8;
typedef __attribute__((ext_vector_type(4))) float f32x4;

#define B_SZ 8192
#define D_INN 4000
#define EMBD 96
#define H0D 2048
#define H1D 1024
#define KDIM 4096  // EMB + D_IN

#define MFMA_BF16 __builtin_amdgcn_mfma_f32_16x16x32_bf16

__device__ __forceinline__ unsigned short f2bf(float f) {
  union { float f; unsigned u; } v; v.f = f;
  unsigned r = v.u + 0x7FFFu + ((v.u >> 16) & 1u);
  return (unsigned short)(r >> 16);
}
__device__ __forceinline__ float bf2f(unsigned short h) {
  union { unsigned u; float f; } v; v.u = ((unsigned)h) << 16;
  return v.f;
}
__device__ __forceinline__ void gld_lds16(const void* g, void* l) {
  __builtin_amdgcn_global_load_lds(
      (const __attribute__((address_space(1))) unsigned int*)g,
      (__attribute__((address_space(3))) unsigned int*)l, 16, 0, 0);
}

// ---- transpose + fp32->bf16 convert: out[c][r] = bf16(in[r][c]) ----
__global__ __launch_bounds__(256) void transpose_cvt(
    const float* __restrict__ in, unsigned short* __restrict__ out, int R, int C) {
  __shared__ float tile[32][33];
  int c0 = blockIdx.x * 32, r0 = blockIdx.y * 32;
  int tc = threadIdx.x & 31, tr = threadIdx.x >> 5;
#pragma unroll
  for (int i = 0; i < 4; ++i) {
    int r = tr + i * 8;
    tile[r][tc] = in[(size_t)(r0 + r) * C + (c0 + tc)];
  }
  __syncthreads();
#pragma unroll
  for (int i = 0; i < 4; ++i) {
    int rr = tr + i * 8;
    out[(size_t)(c0 + rr) * R + (r0 + tc)] = f2bf(tile[tc][rr]);
  }
}

// ---- batched transpose for We: [64][1024][32] f32 -> Wet [64][32][1024] bf16 ----
__global__ __launch_bounds__(256) void transpose_cvt_we(
    const float* __restrict__ in, unsigned short* __restrict__ out) {
  __shared__ float tile[32][33];
  const int e = blockIdx.y, r0 = blockIdx.x * 32;
  const float* src = in + (size_t)e * 32768;
  unsigned short* dst = out + (size_t)e * 32768;
  int tc = threadIdx.x & 31, tr = threadIdx.x >> 5;
#pragma unroll
  for (int i = 0; i < 4; ++i) {
    int r = tr + i * 8;
    tile[r][tc] = src[(size_t)(r0 + r) * 32 + tc];
  }
  __syncthreads();
#pragma unroll
  for (int i = 0; i < 4; ++i) {
    int rr = tr + i * 8;
    dst[(size_t)rr * H1D + r0 + tc] = f2bf(tile[tc][rr]);
  }
}

// ---- build A = [emb_gather | inputs] in bf16, vectorized 8-wide ----
__global__ __launch_bounds__(256) void build_A(
    const float* __restrict__ inputs, const float* __restrict__ emb,
    const int* __restrict__ ballot, const int* __restrict__ contest,
    unsigned short* __restrict__ A) {
  int gid = blockIdx.x * 256 + threadIdx.x;   // chunk of 8 elems
  int b = gid >> 9, c = gid & 511;            // 512 chunks per row of 4096
  const float* src;
  if (c < EMBD / 8) {
    int e = ballot[b] * 8 + contest[b];
    src = emb + (size_t)e * EMBD + c * 8;
  } else {
    src = inputs + (size_t)b * D_INN + (c - EMBD / 8) * 8;
  }
  float4 v0 = *(const float4*)src;
  float4 v1 = *(const float4*)(src + 4);
  unsigned short r[8];
  r[0] = f2bf(v0.x); r[1] = f2bf(v0.y); r[2] = f2bf(v0.z); r[3] = f2bf(v0.w);
  r[4] = f2bf(v1.x); r[5] = f2bf(v1.y); r[6] = f2bf(v1.z); r[7] = f2bf(v1.w);
  *reinterpret_cast<short8*>(A + (size_t)b * KDIM + c * 8) =
      *reinterpret_cast<const short8*>(r);
}

// ---- NT bf16 MFMA GEMM, ring-3 pipelined, two-phase interleave ----
// (round-2 code, verbatim: best-measured GEMM structure, 45% MfmaUtil)
template <int MREP>
__global__ __launch_bounds__(512, 2) void gemm_nt_pipe(
    const unsigned short* __restrict__ A, const unsigned short* __restrict__ Bt,
    const float* __restrict__ bias, unsigned short* __restrict__ C,
    int K, int N, int NBN) {
  constexpr int BM  = MREP * 32;
  constexpr int AI  = MREP / 4;
  constexpr int ASH = BM * 32;
  constexpr int MH  = MREP / 2;
  __shared__ unsigned short lds[3 * ASH + 3 * 8192];

  const int tid = threadIdx.x;
  const int w = tid >> 6, l = tid & 63;
  const int lr = l & 15, kg = l >> 4;
  const int wm = w >> 2, wn = w & 3;

  int swz = (blockIdx.x & 7) * ((int)gridDim.x >> 3) + ((int)blockIdx.x >> 3);
  const int bm = swz / NBN, bn = swz - bm * NBN;
  const int NT = K >> 5;

  const int rg = l >> 2;
  const int sl = ((l & 3) ^ ((l >> 3) & 3)) * 8;
  const unsigned short* ga[AI];
#pragma unroll
  for (int i = 0; i < AI; ++i)
    ga[i] = A + (size_t)(bm * BM + (i * 8 + w) * 16 + rg) * K + sl;
  const unsigned short* gb0 = Bt + (size_t)(bn * 256 + w * 16 + rg) * K + sl;
  const unsigned short* gb1 = gb0 + (size_t)128 * K;

  const int xo = (kg ^ ((lr >> 1) & 3)) << 4;
  const int aoff = (wm * (MREP * 16) + lr) * 64 + xo;
  const int boff = (wn * 64 + lr) * 64 + xo;

  f32x4 acc[MREP][4] = {};

  auto stageA = [&](int t, int rbuf) {
    unsigned short* la = lds + rbuf * ASH + w * 512;
    const int ko = t * 32;
#pragma unroll
    for (int i = 0; i < AI; ++i) gld_lds16(ga[i] + ko, la + i * 4096);
  };
  auto stageB = [&](int t, int rbuf) {
    unsigned short* lb = lds + 3 * ASH + rbuf * 8192 + w * 512;
    const int ko = t * 32;
    gld_lds16(gb0 + ko, lb);
    gld_lds16(gb1 + ko, lb + 4096);
  };

#define WAIT_VM_STEADY() do { \
    if constexpr (AI == 2) asm volatile("s_waitcnt vmcnt(4)" ::: "memory"); \
    else                   asm volatile("s_waitcnt vmcnt(3)" ::: "memory"); \
  } while (0)

  stageA(0, 0); stageB(0, 0);
  stageA(1, 1); stageB(1, 1);
  WAIT_VM_STEADY();
  __builtin_amdgcn_s_barrier();

  int rb = 0;
  for (int t = 0; t < NT; ++t) {
    int rb2 = rb + 2; if (rb2 >= 3) rb2 -= 3;
    const char* pa = (const char*)lds + rb * (ASH * 2) + aoff;
    const char* pb = (const char*)lds + 3 * (ASH * 2) + rb * 16384 + boff;

    short8 a0[MH], bfr[4];
#pragma unroll
    for (int mi = 0; mi < MH; ++mi) a0[mi] = *(const short8*)(pa + mi * 1024);
#pragma unroll
    for (int ni = 0; ni < 4; ++ni)  bfr[ni] = *(const short8*)(pb + ni * 1024);
    if (t + 2 < NT) stageA(t + 2, rb2);
    asm volatile("s_waitcnt lgkmcnt(0)" ::: "memory");
    __builtin_amdgcn_s_barrier();
    __builtin_amdgcn_s_setprio(1);
#pragma unroll
    for (int mi = 0; mi < MH; ++mi)
#pragma unroll
      for (int ni = 0; ni < 4; ++ni)
        acc[mi][ni] = MFMA_BF16(a0[mi], bfr[ni], acc[mi][ni], 0, 0, 0);
    __builtin_amdgcn_s_setprio(0);

    short8 a1[MH];
#pragma unroll
    for (int mi = 0; mi < MH; ++mi) a1[mi] = *(const short8*)(pa + (MH + mi) * 1024);
    if (t + 2 < NT) {
      stageB(t + 2, rb2);
      asm volatile("s_waitcnt lgkmcnt(0)" ::: "memory");
      WAIT_VM_STEADY();
      __builtin_amdgcn_s_barrier();
    } else if (t + 1 < NT) {
      asm volatile("s_waitcnt lgkmcnt(0)" ::: "memory");
      asm volatile("s_waitcnt vmcnt(0)" ::: "memory");
      __builtin_amdgcn_s_barrier();
    } else {
      asm volatile("s_waitcnt lgkmcnt(0)" ::: "memory");
    }
    __builtin_amdgcn_s_setprio(1);
#pragma unroll
    for (int mi = 0; mi < MH; ++mi)
#pragma unroll
      for (int ni = 0; ni < 4; ++ni)
        acc[MH + mi][ni] = MFMA_BF16(a1[mi], bfr[ni], acc[MH + mi][ni], 0, 0, 0);
    __builtin_amdgcn_s_setprio(0);

    rb = rb + 1; if (rb >= 3) rb = 0;
  }

#pragma unroll
  for (int mi = 0; mi < MREP; ++mi) {
    const int row0 = bm * BM + wm * (MREP * 16) + mi * 16 + kg * 4;
#pragma unroll
    for (int ni = 0; ni < 4; ++ni) {
      const int col = bn * 256 + wn * 64 + ni * 16 + lr;
      const float bv = bias[col];
#pragma unroll
      for (int j = 0; j < 4; ++j) {
        float v = acc[mi][ni][j] + bv;
        v = v > 0.f ? v : 0.f;
        C[(size_t)(row0 + j) * N + col] = f2bf(v);
      }
    }
  }
#undef WAIT_VM_STEADY
}

// ---- routed expert head via MFMA: one block per expert (round-6 verified) ----
__global__ __launch_bounds__(256) void expert_head_mfma(
    const unsigned short* __restrict__ h1, const unsigned short* __restrict__ Wet,
    const float* __restrict__ be, const int* __restrict__ ballot,
    const int* __restrict__ contest, float* __restrict__ out) {
  const int e = blockIdx.x;
  __shared__ unsigned short sidx[1024];
  __shared__ int scnt;
  if (threadIdx.x == 0) scnt = 0;
  __syncthreads();
  for (int i = threadIdx.x; i < B_SZ; i += 256)
    if (ballot[i] * 8 + contest[i] == e) {
      int p = atomicAdd(&scnt, 1);
      if (p < 1024) sidx[p] = (unsigned short)i;
    }
  __syncthreads();
  const int cnt = min(scnt, 1024);
  const int w = threadIdx.x >> 6, l = threadIdx.x & 63;
  const int lr = l & 15, kg = l >> 4;
  const unsigned short* wbase = Wet + (size_t)e * 32768;
  for (int c0 = w * 32; c0 < cnt; c0 += 128) {
    const int ns = min(32, cnt - c0);
    f32x4 acc[2][2] = {};
    int ridx[2];
#pragma unroll
    for (int mi = 0; mi < 2; ++mi) {
      int rr = mi * 16 + lr;
      ridx[mi] = sidx[c0 + (rr < ns ? rr : 0)];
    }
#pragma unroll 4
    for (int kk = 0; kk < 32; ++kk) {
      short8 a0 = *(const short8*)(h1 + (size_t)ridx[0] * H1D + kk * 32 + kg * 8);
      short8 a1 = *(const short8*)(h1 + (size_t)ridx[1] * H1D + kk * 32 + kg * 8);
      short8 b0 = *(const short8*)(wbase + (size_t)lr * H1D + kk * 32 + kg * 8);
      short8 b1 = *(const short8*)(wbase + (size_t)(16 + lr) * H1D + kk * 32 + kg * 8);
      acc[0][0] = MFMA_BF16(a0, b0, acc[0][0], 0, 0, 0);
      acc[0][1] = MFMA_BF16(a0, b1, acc[0][1], 0, 0, 0);
      acc[1][0] = MFMA_BF16(a1, b0, acc[1][0], 0, 0, 0);
      acc[1][1] = MFMA_BF16(a1, b1, acc[1][1], 0, 0, 0);
    }
#pragma unroll
    for (int mi = 0; mi < 2; ++mi)
#pragma unroll
      for (int ni = 0; ni < 2; ++ni)
#pragma unroll
        for (int j = 0; j < 4; ++j) {
          int row = mi * 16 + kg * 4 + j;
          int col = ni * 16 + lr;
          if (row < ns) {
            float x = acc[mi][ni][j] + be[e * 32 + col];
            out[(size_t)sidx[c0 + row] * 32 + col] = 1.f / (1.f + expf(-x));
          }
        }
  }
}

extern "C" void kernel_launch(void* const* d_in, const int* in_sizes, int n_in,
                              void* d_out, int out_size, void* d_ws, size_t ws_size,
                              hipStream_t stream) {
  const float* inputs = (const float*)d_in[0];
  const float* emb    = (const float*)d_in[1];
  const float* W0     = (const float*)d_in[2];
  const float* b0     = (const float*)d_in[3];
  const float* W1     = (const float*)d_in[4];
  const float* b1     = (const float*)d_in[5];
  const float* We     = (const float*)d_in[6];
  const float* be     = (const float*)d_in[7];
  const int* ballot   = (const int*)d_in[8];
  const int* contest  = (const int*)d_in[9];
  float* out = (float*)d_out;

  char* ws = (char*)d_ws;
  unsigned short* A   = (unsigned short*)(ws);                 //  67108864 B
  unsigned short* W0t = (unsigned short*)(ws + 67108864);      //  16777216 B
  unsigned short* h0  = (unsigned short*)(ws + 83886080);      //  33554432 B
  unsigned short* W1t = (unsigned short*)(ws + 117440512);     //   4194304 B
  unsigned short* h1  = (unsigned short*)(ws + 121634816);     //  16777216 B
  unsigned short* Wet = (unsigned short*)(ws);                 // reuses A (dead after GEMM1)

  dim3 blk(256);
  transpose_cvt<<<dim3(H0D / 32, KDIM / 32, 1), blk, 0, stream>>>(W0, W0t, KDIM, H0D);
  transpose_cvt<<<dim3(H1D / 32, H0D / 32, 1), blk, 0, stream>>>(W1, W1t, H0D, H1D);
  build_A<<<dim3(B_SZ * 512 / 256), blk, 0, stream>>>(inputs, emb, ballot, contest, A);
  // GEMM1: 256x256 tiles -> 32*8 = 256 blocks, round-2 2-phase ring-3
  gemm_nt_pipe<8><<<dim3((B_SZ / 256) * (H0D / 256)), dim3(512), 0, stream>>>(
      A, W0t, b0, h0, KDIM, H0D, H0D / 256);
  // We transpose into the now-dead A region
  transpose_cvt_we<<<dim3(32, 64), blk, 0, stream>>>(We, Wet);
  // GEMM2: 128x256 tiles -> 64*4 = 256 blocks, round-2 2-phase ring-3
  gemm_nt_pipe<4><<<dim3((B_SZ / 128) * (H1D / 256)), dim3(512), 0, stream>>>(
      h0, W1t, b1, h1, H0D, H1D, H1D / 256);
  // routed head: 64 blocks (one per expert), MFMA matvec
  expert_head_mfma<<<dim3(64), blk, 0, stream>>>(h1, Wet, be, ballot, contest, out);
}

// Round 8
// 242.759 us; speedup vs baseline: 1.5296x; 1.0017x over previous
//
#include <hip/hip_runtime.h>
#include <math.h>

typedef __attribute__((ext_vector_type(8))) short short8;
typedef __attribute__((ext_vector_type(4))) float f32x4;

#define B_SZ 8192
#define D_INN 4000
#define EMBD 96
#define H0D 2048
#define H1D 1024
#define KDIM 4096  // EMB + D_IN

#define MFMA_BF16 __builtin_amdgcn_mfma_f32_16x16x32_bf16

__device__ __forceinline__ unsigned short f2bf(float f) {
  union { float f; unsigned u; } v; v.f = f;
  unsigned r = v.u + 0x7FFFu + ((v.u >> 16) & 1u);
  return (unsigned short)(r >> 16);
}
__device__ __forceinline__ float bf2f(unsigned short h) {
  union { unsigned u; float f; } v; v.u = ((unsigned)h) << 16;
  return v.f;
}
__device__ __forceinline__ void gld_lds16(const void* g, void* l) {
  __builtin_amdgcn_global_load_lds(
      (const __attribute__((address_space(1))) unsigned int*)g,
      (__attribute__((address_space(3))) unsigned int*)l, 16, 0, 0);
}

// ---- transpose + fp32->bf16 convert: out[c][r] = bf16(in[r][c]) ----
__global__ __launch_bounds__(256) void transpose_cvt(
    const float* __restrict__ in, unsigned short* __restrict__ out, int R, int C) {
  __shared__ float tile[32][33];
  int c0 = blockIdx.x * 32, r0 = blockIdx.y * 32;
  int tc = threadIdx.x & 31, tr = threadIdx.x >> 5;
#pragma unroll
  for (int i = 0; i < 4; ++i) {
    int r = tr + i * 8;
    tile[r][tc] = in[(size_t)(r0 + r) * C + (c0 + tc)];
  }
  __syncthreads();
#pragma unroll
  for (int i = 0; i < 4; ++i) {
    int rr = tr + i * 8;
    out[(size_t)(c0 + rr) * R + (r0 + tc)] = f2bf(tile[tc][rr]);
  }
}

// ---- batched transpose for We: [64][1024][32] f32 -> Wet [64][32][1024] bf16 ----
__global__ __launch_bounds__(256) void transpose_cvt_we(
    const float* __restrict__ in, unsigned short* __restrict__ out) {
  __shared__ float tile[32][33];
  const int e = blockIdx.y, r0 = blockIdx.x * 32;
  const float* src = in + (size_t)e * 32768;
  unsigned short* dst = out + (size_t)e * 32768;
  int tc = threadIdx.x & 31, tr = threadIdx.x >> 5;
#pragma unroll
  for (int i = 0; i < 4; ++i) {
    int r = tr + i * 8;
    tile[r][tc] = src[(size_t)(r0 + r) * 32 + tc];
  }
  __syncthreads();
#pragma unroll
  for (int i = 0; i < 4; ++i) {
    int rr = tr + i * 8;
    dst[(size_t)rr * H1D + r0 + tc] = f2bf(tile[tc][rr]);
  }
}

// ---- build A = [emb_gather | inputs] in bf16, vectorized 8-wide ----
__global__ __launch_bounds__(256) void build_A(
    const float* __restrict__ inputs, const float* __restrict__ emb,
    const int* __restrict__ ballot, const int* __restrict__ contest,
    unsigned short* __restrict__ A) {
  int gid = blockIdx.x * 256 + threadIdx.x;   // chunk of 8 elems
  int b = gid >> 9, c = gid & 511;            // 512 chunks per row of 4096
  const float* src;
  if (c < EMBD / 8) {
    int e = ballot[b] * 8 + contest[b];
    src = emb + (size_t)e * EMBD + c * 8;
  } else {
    src = inputs + (size_t)b * D_INN + (c - EMBD / 8) * 8;
  }
  float4 v0 = *(const float4*)src;
  float4 v1 = *(const float4*)(src + 4);
  unsigned short r[8];
  r[0] = f2bf(v0.x); r[1] = f2bf(v0.y); r[2] = f2bf(v0.z); r[3] = f2bf(v0.w);
  r[4] = f2bf(v1.x); r[5] = f2bf(v1.y); r[6] = f2bf(v1.z); r[7] = f2bf(v1.w);
  *reinterpret_cast<short8*>(A + (size_t)b * KDIM + c * 8) =
      *reinterpret_cast<const short8*>(r);
}

// ---- GEMM1: 256x256 tile, 16 waves (1024 thr, 4 waves/SIMD), ring-3 ----
// Same 2-phase ring-3 schedule as the round-2 kernel (best measured), but
// 16 waves in a 4x4 grid (each wave 64x64 out) so 4 waves/SIMD cover the
// per-phase ds_read-drain + barrier window with other waves' MFMAs.
// Staging: thread t = (row tid>>2, 16B slot tid&3); verified XOR swizzle
// slot^((row>>1)&3) applied on the GLOBAL source (linear gld_lds dest) and
// on the ds_read addr (xo) -> 0 bank conflicts. 2 loads/thread/tile,
// ring-3 -> steady-state wait vmcnt(2), never 0 mid-loop.
template <int K>
__global__ __launch_bounds__(1024) void gemm_nt_16w(
    const unsigned short* __restrict__ A, const unsigned short* __restrict__ Bt,
    const float* __restrict__ bias, unsigned short* __restrict__ C,
    int N, int NBN) {
  constexpr int SLOT = 16384;                 // bytes per ring slot (256x32 bf16)
  __shared__ char lds[6 * SLOT];              // A slots 0..2, B slots 3..5 (96 KB)

  const int tid = threadIdx.x;
  const int w = tid >> 6, l = tid & 63;
  const int lr = l & 15, kg = l >> 4;
  const int wm = w >> 2, wn = w & 3;          // 4x4 wave grid

  int swz = (blockIdx.x & 7) * ((int)gridDim.x >> 3) + ((int)blockIdx.x >> 3);
  const int bm = swz / NBN, bn = swz - bm * NBN;
  const int NT = K >> 5;

  // staging source (pre-swizzled slot; LDS dest linear at tid*16B)
  const int srow = tid >> 2;
  const int swzsl = (tid & 3) ^ ((srow >> 1) & 3);
  const unsigned short* gaB = A + (size_t)(bm * 256 + srow) * K + swzsl * 8;
  const unsigned short* gbB = Bt + (size_t)(bn * 256 + srow) * K + swzsl * 8;

  // frag-read byte offsets (swizzled to match)
  const int xo = (kg ^ ((lr >> 1) & 3)) << 4;
  const int aoff = (wm * 64 + lr) * 64 + xo;  // + mi*1024
  const int boff = (wn * 64 + lr) * 64 + xo;  // + ni*1024

  f32x4 acc[4][4] = {};

  auto stageA = [&](int t, int rbuf) {
    gld_lds16(gaB + t * 32, lds + rbuf * SLOT + tid * 16);
  };
  auto stageB = [&](int t, int rbuf) {
    gld_lds16(gbB + t * 32, lds + 3 * SLOT + rbuf * SLOT + tid * 16);
  };

  stageA(0, 0); stageB(0, 0);
  stageA(1, 1); stageB(1, 1);
  asm volatile("s_waitcnt vmcnt(2)" ::: "memory");   // tile 0 landed
  __builtin_amdgcn_s_barrier();

  int rb = 0;
  for (int t = 0; t < NT; ++t) {
    int rb2 = rb + 2; if (rb2 >= 3) rb2 -= 3;
    const char* pa = lds + rb * SLOT + aoff;
    const char* pb = lds + 3 * SLOT + rb * SLOT + boff;

    // ---- phase A: read a0[0..1] + bfr[0..3]; MFMA mi 0..1 ----
    short8 a0[2], bfr[4];
#pragma unroll
    for (int mi = 0; mi < 2; ++mi) a0[mi] = *(const short8*)(pa + mi * 1024);
#pragma unroll
    for (int ni = 0; ni < 4; ++ni) bfr[ni] = *(const short8*)(pb + ni * 1024);
    if (t + 2 < NT) stageA(t + 2, rb2);
    asm volatile("s_waitcnt lgkmcnt(0)" ::: "memory");
    __builtin_amdgcn_s_barrier();
    __builtin_amdgcn_s_setprio(1);
#pragma unroll
    for (int mi = 0; mi < 2; ++mi)
#pragma unroll
      for (int ni = 0; ni < 4; ++ni)
        acc[mi][ni] = MFMA_BF16(a0[mi], bfr[ni], acc[mi][ni], 0, 0, 0);
    __builtin_amdgcn_s_setprio(0);

    // ---- phase B: read a1[0..1]; MFMA mi 2..3 (bfr held) ----
    short8 a1[2];
#pragma unroll
    for (int mi = 0; mi < 2; ++mi) a1[mi] = *(const short8*)(pa + (2 + mi) * 1024);
    if (t + 2 < NT) {
      stageB(t + 2, rb2);
      asm volatile("s_waitcnt lgkmcnt(0)" ::: "memory");
      asm volatile("s_waitcnt vmcnt(2)" ::: "memory");  // t+1 landed, t+2 in flight
      __builtin_amdgcn_s_barrier();
    } else if (t + 1 < NT) {
      asm volatile("s_waitcnt lgkmcnt(0)" ::: "memory");
      asm volatile("s_waitcnt vmcnt(0)" ::: "memory");
      __builtin_amdgcn_s_barrier();
    } else {
      asm volatile("s_waitcnt lgkmcnt(0)" ::: "memory");
    }
    __builtin_amdgcn_s_setprio(1);
#pragma unroll
    for (int mi = 0; mi < 2; ++mi)
#pragma unroll
      for (int ni = 0; ni < 4; ++ni)
        acc[2 + mi][ni] = MFMA_BF16(a1[mi], bfr[ni], acc[2 + mi][ni], 0, 0, 0);
    __builtin_amdgcn_s_setprio(0);

    rb = rb + 1; if (rb >= 3) rb = 0;
  }

  // epilogue: bias + relu + bf16 store.  D: col=lane&15, row=(lane>>4)*4+j
#pragma unroll
  for (int mi = 0; mi < 4; ++mi) {
    const int row0 = bm * 256 + wm * 64 + mi * 16 + kg * 4;
#pragma unroll
    for (int ni = 0; ni < 4; ++ni) {
      const int col = bn * 256 + wn * 64 + ni * 16 + lr;
      const float bv = bias[col];
#pragma unroll
      for (int j = 0; j < 4; ++j) {
        float v = acc[mi][ni][j] + bv;
        v = v > 0.f ? v : 0.f;
        C[(size_t)(row0 + j) * N + col] = f2bf(v);
      }
    }
  }
}

// ---- NT bf16 MFMA GEMM, ring-3 pipelined, two-phase (round-2, GEMM2) ----
template <int MREP>
__global__ __launch_bounds__(512, 2) void gemm_nt_pipe(
    const unsigned short* __restrict__ A, const unsigned short* __restrict__ Bt,
    const float* __restrict__ bias, unsigned short* __restrict__ C,
    int K, int N, int NBN) {
  constexpr int BM  = MREP * 32;
  constexpr int AI  = MREP / 4;
  constexpr int ASH = BM * 32;
  constexpr int MH  = MREP / 2;
  __shared__ unsigned short lds[3 * ASH + 3 * 8192];

  const int tid = threadIdx.x;
  const int w = tid >> 6, l = tid & 63;
  const int lr = l & 15, kg = l >> 4;
  const int wm = w >> 2, wn = w & 3;

  int swz = (blockIdx.x & 7) * ((int)gridDim.x >> 3) + ((int)blockIdx.x >> 3);
  const int bm = swz / NBN, bn = swz - bm * NBN;
  const int NT = K >> 5;

  const int rg = l >> 2;
  const int sl = ((l & 3) ^ ((l >> 3) & 3)) * 8;
  const unsigned short* ga[AI];
#pragma unroll
  for (int i = 0; i < AI; ++i)
    ga[i] = A + (size_t)(bm * BM + (i * 8 + w) * 16 + rg) * K + sl;
  const unsigned short* gb0 = Bt + (size_t)(bn * 256 + w * 16 + rg) * K + sl;
  const unsigned short* gb1 = gb0 + (size_t)128 * K;

  const int xo = (kg ^ ((lr >> 1) & 3)) << 4;
  const int aoff = (wm * (MREP * 16) + lr) * 64 + xo;
  const int boff = (wn * 64 + lr) * 64 + xo;

  f32x4 acc[MREP][4] = {};

  auto stageA = [&](int t, int rbuf) {
    unsigned short* la = lds + rbuf * ASH + w * 512;
    const int ko = t * 32;
#pragma unroll
    for (int i = 0; i < AI; ++i) gld_lds16(ga[i] + ko, la + i * 4096);
  };
  auto stageB = [&](int t, int rbuf) {
    unsigned short* lb = lds + 3 * ASH + rbuf * 8192 + w * 512;
    const int ko = t * 32;
    gld_lds16(gb0 + ko, lb);
    gld_lds16(gb1 + ko, lb + 4096);
  };

#define WAIT_VM_STEADY() do { \
    if constexpr (AI == 2) asm volatile("s_waitcnt vmcnt(4)" ::: "memory"); \
    else                   asm volatile("s_waitcnt vmcnt(3)" ::: "memory"); \
  } while (0)

  stageA(0, 0); stageB(0, 0);
  stageA(1, 1); stageB(1, 1);
  WAIT_VM_STEADY();
  __builtin_amdgcn_s_barrier();

  int rb = 0;
  for (int t = 0; t < NT; ++t) {
    int rb2 = rb + 2; if (rb2 >= 3) rb2 -= 3;
    const char* pa = (const char*)lds + rb * (ASH * 2) + aoff;
    const char* pb = (const char*)lds + 3 * (ASH * 2) + rb * 16384 + boff;

    short8 a0[MH], bfr[4];
#pragma unroll
    for (int mi = 0; mi < MH; ++mi) a0[mi] = *(const short8*)(pa + mi * 1024);
#pragma unroll
    for (int ni = 0; ni < 4; ++ni)  bfr[ni] = *(const short8*)(pb + ni * 1024);
    if (t + 2 < NT) stageA(t + 2, rb2);
    asm volatile("s_waitcnt lgkmcnt(0)" ::: "memory");
    __builtin_amdgcn_s_barrier();
    __builtin_amdgcn_s_setprio(1);
#pragma unroll
    for (int mi = 0; mi < MH; ++mi)
#pragma unroll
      for (int ni = 0; ni < 4; ++ni)
        acc[mi][ni] = MFMA_BF16(a0[mi], bfr[ni], acc[mi][ni], 0, 0, 0);
    __builtin_amdgcn_s_setprio(0);

    short8 a1[MH];
#pragma unroll
    for (int mi = 0; mi < MH; ++mi) a1[mi] = *(const short8*)(pa + (MH + mi) * 1024);
    if (t + 2 < NT) {
      stageB(t + 2, rb2);
      asm volatile("s_waitcnt lgkmcnt(0)" ::: "memory");
      WAIT_VM_STEADY();
      __builtin_amdgcn_s_barrier();
    } else if (t + 1 < NT) {
      asm volatile("s_waitcnt lgkmcnt(0)" ::: "memory");
      asm volatile("s_waitcnt vmcnt(0)" ::: "memory");
      __builtin_amdgcn_s_barrier();
    } else {
      asm volatile("s_waitcnt lgkmcnt(0)" ::: "memory");
    }
    __builtin_amdgcn_s_setprio(1);
#pragma unroll
    for (int mi = 0; mi < MH; ++mi)
#pragma unroll
      for (int ni = 0; ni < 4; ++ni)
        acc[MH + mi][ni] = MFMA_BF16(a1[mi], bfr[ni], acc[MH + mi][ni], 0, 0, 0);
    __builtin_amdgcn_s_setprio(0);

    rb = rb + 1; if (rb >= 3) rb = 0;
  }

#pragma unroll
  for (int mi = 0; mi < MREP; ++mi) {
    const int row0 = bm * BM + wm * (MREP * 16) + mi * 16 + kg * 4;
#pragma unroll
    for (int ni = 0; ni < 4; ++ni) {
      const int col = bn * 256 + wn * 64 + ni * 16 + lr;
      const float bv = bias[col];
#pragma unroll
      for (int j = 0; j < 4; ++j) {
        float v = acc[mi][ni][j] + bv;
        v = v > 0.f ? v : 0.f;
        C[(size_t)(row0 + j) * N + col] = f2bf(v);
      }
    }
  }
#undef WAIT_VM_STEADY
}

// ---- routed expert head via MFMA: one block per expert ----
__global__ __launch_bounds__(256) void expert_head_mfma(
    const unsigned short* __restrict__ h1, const unsigned short* __restrict__ Wet,
    const float* __restrict__ be, const int* __restrict__ ballot,
    const int* __restrict__ contest, float* __restrict__ out) {
  const int e = blockIdx.x;
  __shared__ unsigned short sidx[1024];
  __shared__ int scnt;
  if (threadIdx.x == 0) scnt = 0;
  __syncthreads();
  for (int i = threadIdx.x; i < B_SZ; i += 256)
    if (ballot[i] * 8 + contest[i] == e) {
      int p = atomicAdd(&scnt, 1);
      if (p < 1024) sidx[p] = (unsigned short)i;
    }
  __syncthreads();
  const int cnt = min(scnt, 1024);
  const int w = threadIdx.x >> 6, l = threadIdx.x & 63;
  const int lr = l & 15, kg = l >> 4;
  const unsigned short* wbase = Wet + (size_t)e * 32768;
  for (int c0 = w * 32; c0 < cnt; c0 += 128) {
    const int ns = min(32, cnt - c0);
    f32x4 acc[2][2] = {};
    int ridx[2];
#pragma unroll
    for (int mi = 0; mi < 2; ++mi) {
      int rr = mi * 16 + lr;
      ridx[mi] = sidx[c0 + (rr < ns ? rr : 0)];
    }
#pragma unroll 4
    for (int kk = 0; kk < 32; ++kk) {
      short8 a0 = *(const short8*)(h1 + (size_t)ridx[0] * H1D + kk * 32 + kg * 8);
      short8 a1 = *(const short8*)(h1 + (size_t)ridx[1] * H1D + kk * 32 + kg * 8);
      short8 b0 = *(const short8*)(wbase + (size_t)lr * H1D + kk * 32 + kg * 8);
      short8 b1 = *(const short8*)(wbase + (size_t)(16 + lr) * H1D + kk * 32 + kg * 8);
      acc[0][0] = MFMA_BF16(a0, b0, acc[0][0], 0, 0, 0);
      acc[0][1] = MFMA_BF16(a0, b1, acc[0][1], 0, 0, 0);
      acc[1][0] = MFMA_BF16(a1, b0, acc[1][0], 0, 0, 0);
      acc[1][1] = MFMA_BF16(a1, b1, acc[1][1], 0, 0, 0);
    }
#pragma unroll
    for (int mi = 0; mi < 2; ++mi)
#pragma unroll
      for (int ni = 0; ni < 2; ++ni)
#pragma unroll
        for (int j = 0; j < 4; ++j) {
          int row = mi * 16 + kg * 4 + j;
          int col = ni * 16 + lr;
          if (row < ns) {
            float x = acc[mi][ni][j] + be[e * 32 + col];
            out[(size_t)sidx[c0 + row] * 32 + col] = 1.f / (1.f + expf(-x));
          }
        }
  }
}

extern "C" void kernel_launch(void* const* d_in, const int* in_sizes, int n_in,
                              void* d_out, int out_size, void* d_ws, size_t ws_size,
                              hipStream_t stream) {
  const float* inputs = (const float*)d_in[0];
  const float* emb    = (const float*)d_in[1];
  const float* W0     = (const float*)d_in[2];
  const float* b0     = (const float*)d_in[3];
  const float* W1     = (const float*)d_in[4];
  const float* b1     = (const float*)d_in[5];
  const float* We     = (const float*)d_in[6];
  const float* be     = (const float*)d_in[7];
  const int* ballot   = (const int*)d_in[8];
  const int* contest  = (const int*)d_in[9];
  float* out = (float*)d_out;

  char* ws = (char*)d_ws;
  unsigned short* A   = (unsigned short*)(ws);                 //  67108864 B
  unsigned short* W0t = (unsigned short*)(ws + 67108864);      //  16777216 B
  unsigned short* h0  = (unsigned short*)(ws + 83886080);      //  33554432 B
  unsigned short* W1t = (unsigned short*)(ws + 117440512);     //   4194304 B
  unsigned short* h1  = (unsigned short*)(ws + 121634816);     //  16777216 B
  unsigned short* Wet = (unsigned short*)(ws);                 // reuses A (dead after GEMM1)

  dim3 blk(256);
  transpose_cvt<<<dim3(H0D / 32, KDIM / 32, 1), blk, 0, stream>>>(W0, W0t, KDIM, H0D);
  transpose_cvt<<<dim3(H1D / 32, H0D / 32, 1), blk, 0, stream>>>(W1, W1t, H0D, H1D);
  build_A<<<dim3(B_SZ * 512 / 256), blk, 0, stream>>>(inputs, emb, ballot, contest, A);
  // GEMM1: 256x256 tiles -> 32*8 = 256 blocks, 16-wave (1024 thr) ring-3
  gemm_nt_16w<KDIM><<<dim3(256), dim3(1024), 0, stream>>>(A, W0t, b0, h0, H0D, H0D / 256);
  // We transpose into the now-dead A region
  transpose_cvt_we<<<dim3(32, 64), blk, 0, stream>>>(We, Wet);
  // GEMM2: 128x256 tiles -> 64*4 = 256 blocks, round-2 2-phase ring-3
  gemm_nt_pipe<4><<<dim3((B_SZ / 128) * (H1D / 256)), dim3(512), 0, stream>>>(
      h0, W1t, b1, h1, H0D, H1D, H1D / 256);
  // routed head: 64 blocks (one per expert), MFMA matvec
  expert_head_mfma<<<dim3(64), blk, 0, stream>>>(h1, Wet, be, ballot, contest, out);
}

// Round 9
// 235.681 us; speedup vs baseline: 1.5756x; 1.0300x over previous
//
#include <hip/hip_runtime.h>
#include <math.h>

typedef __attribute__((ext_vector_type(8))) short short8;
typedef __attribute__((ext_vector_type(4))) float f32x4;

#define B_SZ 8192
#define D_INN 4000
#define EMBD 96
#define H0D 2048
#define H1D 1024
#define KDIM 4096  // EMB + D_IN

#define MFMA_BF16 __builtin_amdgcn_mfma_f32_16x16x32_bf16

__device__ __forceinline__ unsigned short f2bf(float f) {
  union { float f; unsigned u; } v; v.f = f;
  unsigned r = v.u + 0x7FFFu + ((v.u >> 16) & 1u);
  return (unsigned short)(r >> 16);
}
__device__ __forceinline__ float bf2f(unsigned short h) {
  union { unsigned u; float f; } v; v.u = ((unsigned)h) << 16;
  return v.f;
}
__device__ __forceinline__ void gld_lds16(const void* g, void* l) {
  __builtin_amdgcn_global_load_lds(
      (const __attribute__((address_space(1))) unsigned int*)g,
      (__attribute__((address_space(3))) unsigned int*)l, 16, 0, 0);
}

// ---- transpose + fp32->bf16 convert: out[c][r] = bf16(in[r][c]) ----
__global__ __launch_bounds__(256) void transpose_cvt(
    const float* __restrict__ in, unsigned short* __restrict__ out, int R, int C) {
  __shared__ float tile[32][33];
  int c0 = blockIdx.x * 32, r0 = blockIdx.y * 32;
  int tc = threadIdx.x & 31, tr = threadIdx.x >> 5;
#pragma unroll
  for (int i = 0; i < 4; ++i) {
    int r = tr + i * 8;
    tile[r][tc] = in[(size_t)(r0 + r) * C + (c0 + tc)];
  }
  __syncthreads();
#pragma unroll
  for (int i = 0; i < 4; ++i) {
    int rr = tr + i * 8;
    out[(size_t)(c0 + rr) * R + (r0 + tc)] = f2bf(tile[tc][rr]);
  }
}

// ---- batched transpose for We: [64][1024][32] f32 -> Wet [64][32][1024] bf16 ----
__global__ __launch_bounds__(256) void transpose_cvt_we(
    const float* __restrict__ in, unsigned short* __restrict__ out) {
  __shared__ float tile[32][33];
  const int e = blockIdx.y, r0 = blockIdx.x * 32;
  const float* src = in + (size_t)e * 32768;
  unsigned short* dst = out + (size_t)e * 32768;
  int tc = threadIdx.x & 31, tr = threadIdx.x >> 5;
#pragma unroll
  for (int i = 0; i < 4; ++i) {
    int r = tr + i * 8;
    tile[r][tc] = src[(size_t)(r0 + r) * 32 + tc];
  }
  __syncthreads();
#pragma unroll
  for (int i = 0; i < 4; ++i) {
    int rr = tr + i * 8;
    dst[(size_t)rr * H1D + r0 + tc] = f2bf(tile[tc][rr]);
  }
}

// ---- build A = [emb_gather | inputs] in bf16, vectorized 8-wide ----
__global__ __launch_bounds__(256) void build_A(
    const float* __restrict__ inputs, const float* __restrict__ emb,
    const int* __restrict__ ballot, const int* __restrict__ contest,
    unsigned short* __restrict__ A) {
  int gid = blockIdx.x * 256 + threadIdx.x;   // chunk of 8 elems
  int b = gid >> 9, c = gid & 511;            // 512 chunks per row of 4096
  const float* src;
  if (c < EMBD / 8) {
    int e = ballot[b] * 8 + contest[b];
    src = emb + (size_t)e * EMBD + c * 8;
  } else {
    src = inputs + (size_t)b * D_INN + (c - EMBD / 8) * 8;
  }
  float4 v0 = *(const float4*)src;
  float4 v1 = *(const float4*)(src + 4);
  unsigned short r[8];
  r[0] = f2bf(v0.x); r[1] = f2bf(v0.y); r[2] = f2bf(v0.z); r[3] = f2bf(v0.w);
  r[4] = f2bf(v1.x); r[5] = f2bf(v1.y); r[6] = f2bf(v1.z); r[7] = f2bf(v1.w);
  *reinterpret_cast<short8*>(A + (size_t)b * KDIM + c * 8) =
      *reinterpret_cast<const short8*>(r);
}

// ---- GEMM1: 256x256 tile, 16 waves (1024 thr), ring-3, ONE barrier/tile ----
// R8 structure minus the mid-tile barrier (audit: stage(t+2) writes the slot
// of tile t-1 whose reads retired before the end-of-(t-1) barrier; intra-tile
// reads hit slot rb != rb2; staged-data visibility comes only from the
// end-of-tile vmcnt(2)+barrier). Compiler now interleaves phase-B ds_reads
// with phase-A MFMAs via its own fine-grained lgkmcnt.
template <int K>
__global__ __launch_bounds__(1024) void gemm_nt_16w(
    const unsigned short* __restrict__ A, const unsigned short* __restrict__ Bt,
    const float* __restrict__ bias, unsigned short* __restrict__ C,
    int N, int NBN) {
  constexpr int SLOT = 16384;                 // bytes per ring slot (256x32 bf16)
  __shared__ char lds[6 * SLOT];              // A slots 0..2, B slots 3..5 (96 KB)

  const int tid = threadIdx.x;
  const int w = tid >> 6, l = tid & 63;
  const int lr = l & 15, kg = l >> 4;
  const int wm = w >> 2, wn = w & 3;          // 4x4 wave grid

  int swz = (blockIdx.x & 7) * ((int)gridDim.x >> 3) + ((int)blockIdx.x >> 3);
  const int bm = swz / NBN, bn = swz - bm * NBN;
  const int NT = K >> 5;

  // staging source (pre-swizzled slot; LDS dest linear at tid*16B)
  const int srow = tid >> 2;
  const int swzsl = (tid & 3) ^ ((srow >> 1) & 3);
  const unsigned short* gaB = A + (size_t)(bm * 256 + srow) * K + swzsl * 8;
  const unsigned short* gbB = Bt + (size_t)(bn * 256 + srow) * K + swzsl * 8;

  // frag-read byte offsets (swizzled to match)
  const int xo = (kg ^ ((lr >> 1) & 3)) << 4;
  const int aoff = (wm * 64 + lr) * 64 + xo;  // + mi*1024
  const int boff = (wn * 64 + lr) * 64 + xo;  // + ni*1024

  f32x4 acc[4][4] = {};

  auto stageA = [&](int t, int rbuf) {
    gld_lds16(gaB + t * 32, lds + rbuf * SLOT + tid * 16);
  };
  auto stageB = [&](int t, int rbuf) {
    gld_lds16(gbB + t * 32, lds + 3 * SLOT + rbuf * SLOT + tid * 16);
  };

  stageA(0, 0); stageB(0, 0);
  stageA(1, 1); stageB(1, 1);
  asm volatile("s_waitcnt vmcnt(2)" ::: "memory");   // tile 0 landed
  __builtin_amdgcn_s_barrier();

  int rb = 0;
  for (int t = 0; t < NT; ++t) {
    int rb2 = rb + 2; if (rb2 >= 3) rb2 -= 3;
    const char* pa = lds + rb * SLOT + aoff;
    const char* pb = lds + 3 * SLOT + rb * SLOT + boff;

    short8 a0[2], bfr[4];
#pragma unroll
    for (int mi = 0; mi < 2; ++mi) a0[mi] = *(const short8*)(pa + mi * 1024);
#pragma unroll
    for (int ni = 0; ni < 4; ++ni) bfr[ni] = *(const short8*)(pb + ni * 1024);
    if (t + 2 < NT) stageA(t + 2, rb2);
    __builtin_amdgcn_s_setprio(1);
#pragma unroll
    for (int mi = 0; mi < 2; ++mi)
#pragma unroll
      for (int ni = 0; ni < 4; ++ni)
        acc[mi][ni] = MFMA_BF16(a0[mi], bfr[ni], acc[mi][ni], 0, 0, 0);
    __builtin_amdgcn_s_setprio(0);

    short8 a1[2];
#pragma unroll
    for (int mi = 0; mi < 2; ++mi) a1[mi] = *(const short8*)(pa + (2 + mi) * 1024);
    if (t + 2 < NT) stageB(t + 2, rb2);
    __builtin_amdgcn_s_setprio(1);
#pragma unroll
    for (int mi = 0; mi < 2; ++mi)
#pragma unroll
      for (int ni = 0; ni < 4; ++ni)
        acc[2 + mi][ni] = MFMA_BF16(a1[mi], bfr[ni], acc[2 + mi][ni], 0, 0, 0);
    __builtin_amdgcn_s_setprio(0);

    if (t + 2 < NT) {
      asm volatile("s_waitcnt vmcnt(2)" ::: "memory");  // t+1 landed, t+2 in flight
      __builtin_amdgcn_s_barrier();
    } else if (t + 1 < NT) {
      asm volatile("s_waitcnt vmcnt(0)" ::: "memory");
      __builtin_amdgcn_s_barrier();
    }
    rb = rb + 1; if (rb >= 3) rb = 0;
  }

  // epilogue: bias + relu + bf16 store.  D: col=lane&15, row=(lane>>4)*4+j
#pragma unroll
  for (int mi = 0; mi < 4; ++mi) {
    const int row0 = bm * 256 + wm * 64 + mi * 16 + kg * 4;
#pragma unroll
    for (int ni = 0; ni < 4; ++ni) {
      const int col = bn * 256 + wn * 64 + ni * 16 + lr;
      const float bv = bias[col];
#pragma unroll
      for (int j = 0; j < 4; ++j) {
        float v = acc[mi][ni][j] + bv;
        v = v > 0.f ? v : 0.f;
        C[(size_t)(row0 + j) * N + col] = f2bf(v);
      }
    }
  }
}

// ---- GEMM2: 128x256 tile, BK=64, 16 waves, ring-3 (144 KB), 1 barrier/tile ----
// Wave (wm,wn) owns 32x64 out. Per tile/wave: 12 ds_read_b128, 16 MFMA.
// Staging: A 16 KB (1 gld/thread), B 32 KB (2 gld/thread); 3 loads/thread/tile
// -> steady-state vmcnt(3). 8-slot XOR swizzle slot^(row&7), pre-applied on
// the global source (linear gld_lds dest) + on the ds_read address.
__global__ __launch_bounds__(1024) void gemm2_16w(
    const unsigned short* __restrict__ A, const unsigned short* __restrict__ Bt,
    const float* __restrict__ bias, unsigned short* __restrict__ C) {
  constexpr int K = H0D, N = H1D, NBN = 4;
  constexpr int ASLOT = 16384, BSLOT = 32768;  // bytes per ring slot
  constexpr int NT = K / 64;
  __shared__ char lds[3 * ASLOT + 3 * BSLOT];  // 147456 B

  const int tid = threadIdx.x;
  const int w = tid >> 6, l = tid & 63;
  const int lr = l & 15, kg = l >> 4;
  const int wm = w >> 2, wn = w & 3;

  int swz = (blockIdx.x & 7) * ((int)gridDim.x >> 3) + ((int)blockIdx.x >> 3);
  const int bm = swz / NBN, bn = swz - bm * NBN;

  // staging source (pre-swizzled 16B slot of 8; LDS dest linear tid*16)
  const int srow = tid >> 3;                      // 0..127
  const int sslot = (tid & 7) ^ (srow & 7);       // pre-swizzled slot
  const unsigned short* gaB = A + (size_t)(bm * 128 + srow) * K + sslot * 8;
  const unsigned short* gb0 = Bt + (size_t)(bn * 256 + srow) * K + sslot * 8;
  const unsigned short* gb1 = gb0 + (size_t)128 * K;

  f32x4 acc[2][4] = {};

  auto stage = [&](int t, int rbuf) {
    gld_lds16(gaB + t * 64, lds + rbuf * ASLOT + tid * 16);
    char* lb = lds + 3 * ASLOT + rbuf * BSLOT + tid * 16;
    gld_lds16(gb0 + t * 64, lb);
    gld_lds16(gb1 + t * 64, lb + 16384);
  };

  // frag read (swizzled): row stride 128B, slot = (ks*4+kg) ^ (row&7)
  auto rdrow = [&](const char* base, int row, int ks) -> short8 {
    return *(const short8*)(base + row * 128 + (((ks << 2) | kg) ^ (row & 7)) * 16);
  };

  stage(0, 0);
  stage(1, 1);
  asm volatile("s_waitcnt vmcnt(3)" ::: "memory");   // tile 0 landed
  __builtin_amdgcn_s_barrier();

  int rb = 0;
  for (int t = 0; t < NT; ++t) {
    int rb2 = rb + 2; if (rb2 >= 3) rb2 -= 3;
    const char* pa = lds + rb * ASLOT;
    const char* pb = lds + 3 * ASLOT + rb * BSLOT;

    short8 a[2][2], b[4][2];
#pragma unroll
    for (int mi = 0; mi < 2; ++mi)
#pragma unroll
      for (int ks = 0; ks < 2; ++ks)
        a[mi][ks] = rdrow(pa, wm * 32 + mi * 16 + lr, ks);
#pragma unroll
    for (int ni = 0; ni < 4; ++ni)
#pragma unroll
      for (int ks = 0; ks < 2; ++ks)
        b[ni][ks] = rdrow(pb, wn * 64 + ni * 16 + lr, ks);
    if (t + 2 < NT) stage(t + 2, rb2);
    __builtin_amdgcn_s_setprio(1);
#pragma unroll
    for (int mi = 0; mi < 2; ++mi)
#pragma unroll
      for (int ni = 0; ni < 4; ++ni)
#pragma unroll
        for (int ks = 0; ks < 2; ++ks)
          acc[mi][ni] = MFMA_BF16(a[mi][ks], b[ni][ks], acc[mi][ni], 0, 0, 0);
    __builtin_amdgcn_s_setprio(0);

    if (t + 2 < NT) {
      asm volatile("s_waitcnt vmcnt(3)" ::: "memory");  // t+1 landed
      __builtin_amdgcn_s_barrier();
    } else if (t + 1 < NT) {
      asm volatile("s_waitcnt vmcnt(0)" ::: "memory");
      __builtin_amdgcn_s_barrier();
    }
    rb = rb + 1; if (rb >= 3) rb = 0;
  }

  // epilogue
#pragma unroll
  for (int mi = 0; mi < 2; ++mi) {
    const int row0 = bm * 128 + wm * 32 + mi * 16 + kg * 4;
#pragma unroll
    for (int ni = 0; ni < 4; ++ni) {
      const int col = bn * 256 + wn * 64 + ni * 16 + lr;
      const float bv = bias[col];
#pragma unroll
      for (int j = 0; j < 4; ++j) {
        float v = acc[mi][ni][j] + bv;
        v = v > 0.f ? v : 0.f;
        C[(size_t)(row0 + j) * N + col] = f2bf(v);
      }
    }
  }
}

// ---- routed expert head via MFMA: one block per expert ----
__global__ __launch_bounds__(256) void expert_head_mfma(
    const unsigned short* __restrict__ h1, const unsigned short* __restrict__ Wet,
    const float* __restrict__ be, const int* __restrict__ ballot,
    const int* __restrict__ contest, float* __restrict__ out) {
  const int e = blockIdx.x;
  __shared__ unsigned short sidx[1024];
  __shared__ int scnt;
  if (threadIdx.x == 0) scnt = 0;
  __syncthreads();
  for (int i = threadIdx.x; i < B_SZ; i += 256)
    if (ballot[i] * 8 + contest[i] == e) {
      int p = atomicAdd(&scnt, 1);
      if (p < 1024) sidx[p] = (unsigned short)i;
    }
  __syncthreads();
  const int cnt = min(scnt, 1024);
  const int w = threadIdx.x >> 6, l = threadIdx.x & 63;
  const int lr = l & 15, kg = l >> 4;
  const unsigned short* wbase = Wet + (size_t)e * 32768;
  for (int c0 = w * 32; c0 < cnt; c0 += 128) {
    const int ns = min(32, cnt - c0);
    f32x4 acc[2][2] = {};
    int ridx[2];
#pragma unroll
    for (int mi = 0; mi < 2; ++mi) {
      int rr = mi * 16 + lr;
      ridx[mi] = sidx[c0 + (rr < ns ? rr : 0)];
    }
#pragma unroll 4
    for (int kk = 0; kk < 32; ++kk) {
      short8 a0 = *(const short8*)(h1 + (size_t)ridx[0] * H1D + kk * 32 + kg * 8);
      short8 a1 = *(const short8*)(h1 + (size_t)ridx[1] * H1D + kk * 32 + kg * 8);
      short8 b0 = *(const short8*)(wbase + (size_t)lr * H1D + kk * 32 + kg * 8);
      short8 b1 = *(const short8*)(wbase + (size_t)(16 + lr) * H1D + kk * 32 + kg * 8);
      acc[0][0] = MFMA_BF16(a0, b0, acc[0][0], 0, 0, 0);
      acc[0][1] = MFMA_BF16(a0, b1, acc[0][1], 0, 0, 0);
      acc[1][0] = MFMA_BF16(a1, b0, acc[1][0], 0, 0, 0);
      acc[1][1] = MFMA_BF16(a1, b1, acc[1][1], 0, 0, 0);
    }
#pragma unroll
    for (int mi = 0; mi < 2; ++mi)
#pragma unroll
      for (int ni = 0; ni < 2; ++ni)
#pragma unroll
        for (int j = 0; j < 4; ++j) {
          int row = mi * 16 + kg * 4 + j;
          int col = ni * 16 + lr;
          if (row < ns) {
            float x = acc[mi][ni][j] + be[e * 32 + col];
            out[(size_t)sidx[c0 + row] * 32 + col] = 1.f / (1.f + expf(-x));
          }
        }
  }
}

extern "C" void kernel_launch(void* const* d_in, const int* in_sizes, int n_in,
                              void* d_out, int out_size, void* d_ws, size_t ws_size,
                              hipStream_t stream) {
  const float* inputs = (const float*)d_in[0];
  const float* emb    = (const float*)d_in[1];
  const float* W0     = (const float*)d_in[2];
  const float* b0     = (const float*)d_in[3];
  const float* W1     = (const float*)d_in[4];
  const float* b1     = (const float*)d_in[5];
  const float* We     = (const float*)d_in[6];
  const float* be     = (const float*)d_in[7];
  const int* ballot   = (const int*)d_in[8];
  const int* contest  = (const int*)d_in[9];
  float* out = (float*)d_out;

  char* ws = (char*)d_ws;
  unsigned short* A   = (unsigned short*)(ws);                 //  67108864 B
  unsigned short* W0t = (unsigned short*)(ws + 67108864);      //  16777216 B
  unsigned short* h0  = (unsigned short*)(ws + 83886080);      //  33554432 B
  unsigned short* W1t = (unsigned short*)(ws + 117440512);     //   4194304 B
  unsigned short* h1  = (unsigned short*)(ws + 121634816);     //  16777216 B
  unsigned short* Wet = (unsigned short*)(ws);                 // reuses A (dead after GEMM1)

  dim3 blk(256);
  transpose_cvt<<<dim3(H0D / 32, KDIM / 32, 1), blk, 0, stream>>>(W0, W0t, KDIM, H0D);
  transpose_cvt<<<dim3(H1D / 32, H0D / 32, 1), blk, 0, stream>>>(W1, W1t, H0D, H1D);
  build_A<<<dim3(B_SZ * 512 / 256), blk, 0, stream>>>(inputs, emb, ballot, contest, A);
  // GEMM1: 256x256 tiles -> 256 blocks, 16-wave ring-3, 1 barrier/tile
  gemm_nt_16w<KDIM><<<dim3(256), dim3(1024), 0, stream>>>(A, W0t, b0, h0, H0D, H0D / 256);
  // We transpose into the now-dead A region
  transpose_cvt_we<<<dim3(32, 64), blk, 0, stream>>>(We, Wet);
  // GEMM2: 128x256 tiles -> 256 blocks, 16-wave BK=64 ring-3, 1 barrier/tile
  gemm2_16w<<<dim3(256), dim3(1024), 0, stream>>>(h0, W1t, b1, h1);
  // routed head: 64 blocks (one per expert), MFMA matvec
  expert_head_mfma<<<dim3(64), blk, 0, stream>>>(h1, Wet, be, ballot, contest, out);
}

// Round 11
// 220.370 us; speedup vs baseline: 1.6850x; 1.0695x over previous
//
#include <hip/hip_runtime.h>
#include <math.h>

typedef __attribute__((ext_vector_type(8))) short short8;
typedef __attribute__((ext_vector_type(4))) float f32x4;

#define B_SZ 8192
#define D_INN 4000
#define EMBD 96
#define H0D 2048
#define H1D 1024
#define KDIM 4096  // EMB + D_IN

#define MFMA_BF16 __builtin_amdgcn_mfma_f32_16x16x32_bf16

__device__ __forceinline__ unsigned short f2bf(float f) {
  union { float f; unsigned u; } v; v.f = f;
  unsigned r = v.u + 0x7FFFu + ((v.u >> 16) & 1u);
  return (unsigned short)(r >> 16);
}
__device__ __forceinline__ float bf2f(unsigned short h) {
  union { unsigned u; float f; } v; v.u = ((unsigned)h) << 16;
  return v.f;
}
__device__ __forceinline__ void gld_lds16(const void* g, void* l) {
  __builtin_amdgcn_global_load_lds(
      (const __attribute__((address_space(1))) unsigned int*)g,
      (__attribute__((address_space(3))) unsigned int*)l, 16, 0, 0);
}

// ---- merged transpose+cvt: W0 and W1 in ONE launch (range dispatch) ----
// W0 [4096][2048]->W0t[2048][4096] (8192 blks); W1 [2048][1024]->W1t (2048).
__global__ __launch_bounds__(256) void transpose_w01(
    const float* __restrict__ W0, const float* __restrict__ W1,
    unsigned short* __restrict__ W0t, unsigned short* __restrict__ W1t) {
  __shared__ float tile[32][33];
  const int bid = blockIdx.x;
  const float* in; unsigned short* out; int R, C, c0, r0;
  if (bid < 8192) {
    in = W0; out = W0t; R = KDIM; C = H0D;
    c0 = (bid & 63) * 32; r0 = (bid >> 6) * 32;
  } else {
    int x = bid - 8192;
    in = W1; out = W1t; R = H0D; C = H1D;
    c0 = (x & 31) * 32; r0 = (x >> 5) * 32;
  }
  int tc = threadIdx.x & 31, tr = threadIdx.x >> 5;
#pragma unroll
  for (int i = 0; i < 4; ++i) {
    int r = tr + i * 8;
    tile[r][tc] = in[(size_t)(r0 + r) * C + (c0 + tc)];
  }
  __syncthreads();
#pragma unroll
  for (int i = 0; i < 4; ++i) {
    int rr = tr + i * 8;
    out[(size_t)(c0 + rr) * R + (r0 + tc)] = f2bf(tile[tc][rr]);
  }
}

// ---- batched transpose for We: [64][1024][32] f32 -> Wet [64][32][1024] bf16 ----
// (launched AFTER GEMM1; Wet aliases the then-dead A buffer)
__global__ __launch_bounds__(256) void transpose_cvt_we(
    const float* __restrict__ in, unsigned short* __restrict__ out) {
  __shared__ float tile[32][33];
  const int e = blockIdx.y, r0 = blockIdx.x * 32;
  const float* src = in + (size_t)e * 32768;
  unsigned short* dst = out + (size_t)e * 32768;
  int tc = threadIdx.x & 31, tr = threadIdx.x >> 5;
#pragma unroll
  for (int i = 0; i < 4; ++i) {
    int r = tr + i * 8;
    tile[r][tc] = src[(size_t)(r0 + r) * 32 + tc];
  }
  __syncthreads();
#pragma unroll
  for (int i = 0; i < 4; ++i) {
    int rr = tr + i * 8;
    dst[(size_t)rr * H1D + r0 + tc] = f2bf(tile[tc][rr]);
  }
}

// ---- build A = [emb_gather | inputs] in bf16, vectorized 8-wide ----
__global__ __launch_bounds__(256) void build_A(
    const float* __restrict__ inputs, const float* __restrict__ emb,
    const int* __restrict__ ballot, const int* __restrict__ contest,
    unsigned short* __restrict__ A) {
  int gid = blockIdx.x * 256 + threadIdx.x;   // chunk of 8 elems
  int b = gid >> 9, c = gid & 511;            // 512 chunks per row of 4096
  const float* src;
  if (c < EMBD / 8) {
    int e = ballot[b] * 8 + contest[b];
    src = emb + (size_t)e * EMBD + c * 8;
  } else {
    src = inputs + (size_t)b * D_INN + (c - EMBD / 8) * 8;
  }
  float4 v0 = *(const float4*)src;
  float4 v1 = *(const float4*)(src + 4);
  unsigned short r[8];
  r[0] = f2bf(v0.x); r[1] = f2bf(v0.y); r[2] = f2bf(v0.z); r[3] = f2bf(v0.w);
  r[4] = f2bf(v1.x); r[5] = f2bf(v1.y); r[6] = f2bf(v1.z); r[7] = f2bf(v1.w);
  *reinterpret_cast<short8*>(A + (size_t)b * KDIM + c * 8) =
      *reinterpret_cast<const short8*>(r);
}

// ---- GEMM1: 256x256 tile, 16 waves (1024 thr), ring-3, 1 barrier/tile ----
// (round-9 version, unchanged: best-measured GEMM1, 54-56% MfmaUtil)
template <int K>
__global__ __launch_bounds__(1024) void gemm_nt_16w(
    const unsigned short* __restrict__ A, const unsigned short* __restrict__ Bt,
    const float* __restrict__ bias, unsigned short* __restrict__ C,
    int N, int NBN) {
  constexpr int SLOT = 16384;                 // bytes per ring slot (256x32 bf16)
  __shared__ char lds[6 * SLOT];              // A slots 0..2, B slots 3..5 (96 KB)

  const int tid = threadIdx.x;
  const int w = tid >> 6, l = tid & 63;
  const int lr = l & 15, kg = l >> 4;
  const int wm = w >> 2, wn = w & 3;          // 4x4 wave grid

  int swz = (blockIdx.x & 7) * ((int)gridDim.x >> 3) + ((int)blockIdx.x >> 3);
  const int bm = swz / NBN, bn = swz - bm * NBN;
  const int NT = K >> 5;

  const int srow = tid >> 2;
  const int swzsl = (tid & 3) ^ ((srow >> 1) & 3);
  const unsigned short* gaB = A + (size_t)(bm * 256 + srow) * K + swzsl * 8;
  const unsigned short* gbB = Bt + (size_t)(bn * 256 + srow) * K + swzsl * 8;

  const int xo = (kg ^ ((lr >> 1) & 3)) << 4;
  const int aoff = (wm * 64 + lr) * 64 + xo;
  const int boff = (wn * 64 + lr) * 64 + xo;

  f32x4 acc[4][4] = {};

  auto stageA = [&](int t, int rbuf) {
    gld_lds16(gaB + t * 32, lds + rbuf * SLOT + tid * 16);
  };
  auto stageB = [&](int t, int rbuf) {
    gld_lds16(gbB + t * 32, lds + 3 * SLOT + rbuf * SLOT + tid * 16);
  };

  stageA(0, 0); stageB(0, 0);
  stageA(1, 1); stageB(1, 1);
  asm volatile("s_waitcnt vmcnt(2)" ::: "memory");
  __builtin_amdgcn_s_barrier();

  int rb = 0;
  for (int t = 0; t < NT; ++t) {
    int rb2 = rb + 2; if (rb2 >= 3) rb2 -= 3;
    const char* pa = lds + rb * SLOT + aoff;
    const char* pb = lds + 3 * SLOT + rb * SLOT + boff;

    short8 a0[2], bfr[4];
#pragma unroll
    for (int mi = 0; mi < 2; ++mi) a0[mi] = *(const short8*)(pa + mi * 1024);
#pragma unroll
    for (int ni = 0; ni < 4; ++ni) bfr[ni] = *(const short8*)(pb + ni * 1024);
    if (t + 2 < NT) stageA(t + 2, rb2);
    __builtin_amdgcn_s_setprio(1);
#pragma unroll
    for (int mi = 0; mi < 2; ++mi)
#pragma unroll
      for (int ni = 0; ni < 4; ++ni)
        acc[mi][ni] = MFMA_BF16(a0[mi], bfr[ni], acc[mi][ni], 0, 0, 0);
    __builtin_amdgcn_s_setprio(0);

    short8 a1[2];
#pragma unroll
    for (int mi = 0; mi < 2; ++mi) a1[mi] = *(const short8*)(pa + (2 + mi) * 1024);
    if (t + 2 < NT) stageB(t + 2, rb2);
    __builtin_amdgcn_s_setprio(1);
#pragma unroll
    for (int mi = 0; mi < 2; ++mi)
#pragma unroll
      for (int ni = 0; ni < 4; ++ni)
        acc[2 + mi][ni] = MFMA_BF16(a1[mi], bfr[ni], acc[2 + mi][ni], 0, 0, 0);
    __builtin_amdgcn_s_setprio(0);

    if (t + 2 < NT) {
      asm volatile("s_waitcnt vmcnt(2)" ::: "memory");
      __builtin_amdgcn_s_barrier();
    } else if (t + 1 < NT) {
      asm volatile("s_waitcnt vmcnt(0)" ::: "memory");
      __builtin_amdgcn_s_barrier();
    }
    rb = rb + 1; if (rb >= 3) rb = 0;
  }

#pragma unroll
  for (int mi = 0; mi < 4; ++mi) {
    const int row0 = bm * 256 + wm * 64 + mi * 16 + kg * 4;
#pragma unroll
    for (int ni = 0; ni < 4; ++ni) {
      const int col = bn * 256 + wn * 64 + ni * 16 + lr;
      const float bv = bias[col];
#pragma unroll
      for (int j = 0; j < 4; ++j) {
        float v = acc[mi][ni][j] + bv;
        v = v > 0.f ? v : 0.f;
        C[(size_t)(row0 + j) * N + col] = f2bf(v);
      }
    }
  }
}

// ---- GEMM2: 128x256 tile, 8 waves (512 thr), wave 64x64, BK=32 ring-3 ----
__global__ __launch_bounds__(512) void gemm2_8w(
    const unsigned short* __restrict__ A, const unsigned short* __restrict__ Bt,
    const float* __restrict__ bias, unsigned short* __restrict__ C) {
  constexpr int K = H0D, N = H1D, NBN = 4;
  constexpr int ASLOT = 8192, BSLOT = 16384;
  constexpr int NT = K >> 5;                   // 64
  __shared__ char lds[3 * (ASLOT + BSLOT)];    // 73728 B

  const int tid = threadIdx.x;
  const int w = tid >> 6, l = tid & 63;
  const int lr = l & 15, kg = l >> 4;
  const int wm = w >> 2, wn = w & 3;

  int swz = (blockIdx.x & 7) * ((int)gridDim.x >> 3) + ((int)blockIdx.x >> 3);
  const int bm = swz / NBN, bn = swz - bm * NBN;

  const int srow = tid >> 2;                   // 0..127
  const int swzsl = (tid & 3) ^ ((srow >> 1) & 3);
  const unsigned short* gaB = A + (size_t)(bm * 128 + srow) * K + swzsl * 8;
  const unsigned short* gb0 = Bt + (size_t)(bn * 256 + srow) * K + swzsl * 8;
  const unsigned short* gb1 = gb0 + (size_t)128 * K;

  const int xo = (kg ^ ((lr >> 1) & 3)) << 4;
  const int aoff = (wm * 64 + lr) * 64 + xo;   // + mi*1024 (rows 0..127)
  const int boff = (wn * 64 + lr) * 64 + xo;   // + ni*1024 (rows 0..255)

  f32x4 acc[4][4] = {};

  auto stage = [&](int t, int rbuf) {
    gld_lds16(gaB + t * 32, lds + rbuf * ASLOT + tid * 16);
    char* lb = lds + 3 * ASLOT + rbuf * BSLOT + tid * 16;
    gld_lds16(gb0 + t * 32, lb);
    gld_lds16(gb1 + t * 32, lb + 8192);
  };

  stage(0, 0);
  stage(1, 1);
  asm volatile("s_waitcnt vmcnt(3)" ::: "memory");   // tile 0 landed
  __builtin_amdgcn_s_barrier();

  int rb = 0;
  for (int t = 0; t < NT; ++t) {
    int rb2 = rb + 2; if (rb2 >= 3) rb2 -= 3;
    const char* pa = lds + rb * ASLOT + aoff;
    const char* pb = lds + 3 * ASLOT + rb * BSLOT + boff;

    short8 a[4], b[4];
#pragma unroll
    for (int mi = 0; mi < 4; ++mi) a[mi] = *(const short8*)(pa + mi * 1024);
#pragma unroll
    for (int ni = 0; ni < 4; ++ni) b[ni] = *(const short8*)(pb + ni * 1024);
    if (t + 2 < NT) stage(t + 2, rb2);
    __builtin_amdgcn_s_setprio(1);
#pragma unroll
    for (int mi = 0; mi < 4; ++mi)
#pragma unroll
      for (int ni = 0; ni < 4; ++ni)
        acc[mi][ni] = MFMA_BF16(a[mi], b[ni], acc[mi][ni], 0, 0, 0);
    __builtin_amdgcn_s_setprio(0);

    if (t + 2 < NT) {
      asm volatile("s_waitcnt vmcnt(3)" ::: "memory");  // t+1 landed
      __builtin_amdgcn_s_barrier();
    } else if (t + 1 < NT) {
      asm volatile("s_waitcnt vmcnt(0)" ::: "memory");
      __builtin_amdgcn_s_barrier();
    }
    rb = rb + 1; if (rb >= 3) rb = 0;
  }

#pragma unroll
  for (int mi = 0; mi < 4; ++mi) {
    const int row0 = bm * 128 + wm * 64 + mi * 16 + kg * 4;
#pragma unroll
    for (int ni = 0; ni < 4; ++ni) {
      const int col = bn * 256 + wn * 64 + ni * 16 + lr;
      const float bv = bias[col];
#pragma unroll
      for (int j = 0; j < 4; ++j) {
        float v = acc[mi][ni][j] + bv;
        v = v > 0.f ? v : 0.f;
        C[(size_t)(row0 + j) * N + col] = f2bf(v);
      }
    }
  }
}

// ---- routed expert head via MFMA: 128 blocks = expert x sample-half ----
__global__ __launch_bounds__(256) void expert_head_mfma(
    const unsigned short* __restrict__ h1, const unsigned short* __restrict__ Wet,
    const float* __restrict__ be, const int* __restrict__ ballot,
    const int* __restrict__ contest, float* __restrict__ out) {
  const int e = blockIdx.x >> 1, half = blockIdx.x & 1;
  __shared__ unsigned short sidx[1024];
  __shared__ int scnt;
  if (threadIdx.x == 0) scnt = 0;
  __syncthreads();
  const int lo = half * (B_SZ / 2), hi = lo + B_SZ / 2;
  for (int i = lo + threadIdx.x; i < hi; i += 256)
    if (ballot[i] * 8 + contest[i] == e) {
      int p = atomicAdd(&scnt, 1);
      if (p < 1024) sidx[p] = (unsigned short)i;
    }
  __syncthreads();
  const int cnt = min(scnt, 1024);
  const int w = threadIdx.x >> 6, l = threadIdx.x & 63;
  const int lr = l & 15, kg = l >> 4;
  const unsigned short* wbase = Wet + (size_t)e * 32768;
  for (int c0 = w * 32; c0 < cnt; c0 += 128) {
    const int ns = min(32, cnt - c0);
    f32x4 acc[2][2] = {};
    int ridx[2];
#pragma unroll
    for (int mi = 0; mi < 2; ++mi) {
      int rr = mi * 16 + lr;
      ridx[mi] = sidx[c0 + (rr < ns ? rr : 0)];
    }
#pragma unroll 4
    for (int kk = 0; kk < 32; ++kk) {
      short8 a0 = *(const short8*)(h1 + (size_t)ridx[0] * H1D + kk * 32 + kg * 8);
      short8 a1 = *(const short8*)(h1 + (size_t)ridx[1] * H1D + kk * 32 + kg * 8);
      short8 b0 = *(const short8*)(wbase + (size_t)lr * H1D + kk * 32 + kg * 8);
      short8 b1 = *(const short8*)(wbase + (size_t)(16 + lr) * H1D + kk * 32 + kg * 8);
      acc[0][0] = MFMA_BF16(a0, b0, acc[0][0], 0, 0, 0);
      acc[0][1] = MFMA_BF16(a0, b1, acc[0][1], 0, 0, 0);
      acc[1][0] = MFMA_BF16(a1, b0, acc[1][0], 0, 0, 0);
      acc[1][1] = MFMA_BF16(a1, b1, acc[1][1], 0, 0, 0);
    }
#pragma unroll
    for (int mi = 0; mi < 2; ++mi)
#pragma unroll
      for (int ni = 0; ni < 2; ++ni)
#pragma unroll
        for (int j = 0; j < 4; ++j) {
          int row = mi * 16 + kg * 4 + j;
          int col = ni * 16 + lr;
          if (row < ns) {
            float x = acc[mi][ni][j] + be[e * 32 + col];
            out[(size_t)sidx[c0 + row] * 32 + col] = 1.f / (1.f + expf(-x));
          }
        }
  }
}

extern "C" void kernel_launch(void* const* d_in, const int* in_sizes, int n_in,
                              void* d_out, int out_size, void* d_ws, size_t ws_size,
                              hipStream_t stream) {
  const float* inputs = (const float*)d_in[0];
  const float* emb    = (const float*)d_in[1];
  const float* W0     = (const float*)d_in[2];
  const float* b0     = (const float*)d_in[3];
  const float* W1     = (const float*)d_in[4];
  const float* b1     = (const float*)d_in[5];
  const float* We     = (const float*)d_in[6];
  const float* be     = (const float*)d_in[7];
  const int* ballot   = (const int*)d_in[8];
  const int* contest  = (const int*)d_in[9];
  float* out = (float*)d_out;

  char* ws = (char*)d_ws;
  unsigned short* A   = (unsigned short*)(ws);                 //  67108864 B
  unsigned short* W0t = (unsigned short*)(ws + 67108864);      //  16777216 B
  unsigned short* h0  = (unsigned short*)(ws + 83886080);      //  33554432 B
  unsigned short* W1t = (unsigned short*)(ws + 117440512);     //   4194304 B
  unsigned short* h1  = (unsigned short*)(ws + 121634816);     //  16777216 B
  unsigned short* Wet = (unsigned short*)(ws);                 // aliases A (dead after GEMM1)

  dim3 blk(256);
  // W0 + W1 transposes in one launch (10240 blocks)
  transpose_w01<<<dim3(10240), blk, 0, stream>>>(W0, W1, W0t, W1t);
  build_A<<<dim3(B_SZ * 512 / 256), blk, 0, stream>>>(inputs, emb, ballot, contest, A);
  // GEMM1: 256x256 tiles -> 256 blocks, 16-wave ring-3, 1 barrier/tile
  gemm_nt_16w<KDIM><<<dim3(256), dim3(1024), 0, stream>>>(A, W0t, b0, h0, H0D, H0D / 256);
  // We transpose into the now-dead A region
  transpose_cvt_we<<<dim3(32, 64), blk, 0, stream>>>(We, Wet);
  // GEMM2: 128x256 tiles -> 256 blocks, 8-wave wave-64x64 ring-3
  gemm2_8w<<<dim3(256), dim3(512), 0, stream>>>(h0, W1t, b1, h1);
  // routed head: 128 blocks (expert x sample-half), MFMA matvec
  expert_head_mfma<<<dim3(128), blk, 0, stream>>>(h1, Wet, be, ballot, contest, out);
}

// Round 12
// 215.177 us; speedup vs baseline: 1.7257x; 1.0241x over previous
//
#include <hip/hip_runtime.h>
#include <math.h>

typedef __attribute__((ext_vector_type(8))) short short8;
typedef __attribute__((ext_vector_type(4))) float f32x4;

#define B_SZ 8192
#define D_INN 4000
#define EMBD 96
#define H0D 2048
#define H1D 1024
#define KDIM 4096  // EMB + D_IN

#define MFMA_BF16 __builtin_amdgcn_mfma_f32_16x16x32_bf16

__device__ __forceinline__ unsigned short f2bf(float f) {
  union { float f; unsigned u; } v; v.f = f;
  unsigned r = v.u + 0x7FFFu + ((v.u >> 16) & 1u);
  return (unsigned short)(r >> 16);
}
__device__ __forceinline__ float bf2f(unsigned short h) {
  union { unsigned u; float f; } v; v.u = ((unsigned)h) << 16;
  return v.f;
}
__device__ __forceinline__ void gld_lds16(const void* g, void* l) {
  __builtin_amdgcn_global_load_lds(
      (const __attribute__((address_space(1))) unsigned int*)g,
      (__attribute__((address_space(3))) unsigned int*)l, 16, 0, 0);
}

// ---- merged prep: W0/W1 transpose+cvt AND build_A, one launch ----
// blocks [0,8192): W0 [4096][2048]->W0t[2048][4096]
// blocks [8192,10240): W1 [2048][1024]->W1t[1024][2048]
// blocks [10240,26624): build A = [emb_gather | inputs] bf16 (8-wide)
__global__ __launch_bounds__(256) void prep_inputs(
    const float* __restrict__ W0, const float* __restrict__ W1,
    unsigned short* __restrict__ W0t, unsigned short* __restrict__ W1t,
    const float* __restrict__ inputs, const float* __restrict__ emb,
    const int* __restrict__ ballot, const int* __restrict__ contest,
    unsigned short* __restrict__ A) {
  const int bid = blockIdx.x;
  if (bid < 10240) {
    __shared__ float tile[32][33];
    const float* in; unsigned short* out; int R, C, c0, r0;
    if (bid < 8192) {
      in = W0; out = W0t; R = KDIM; C = H0D;
      c0 = (bid & 63) * 32; r0 = (bid >> 6) * 32;
    } else {
      int x = bid - 8192;
      in = W1; out = W1t; R = H0D; C = H1D;
      c0 = (x & 31) * 32; r0 = (x >> 5) * 32;
    }
    int tc = threadIdx.x & 31, tr = threadIdx.x >> 5;
#pragma unroll
    for (int i = 0; i < 4; ++i) {
      int r = tr + i * 8;
      tile[r][tc] = in[(size_t)(r0 + r) * C + (c0 + tc)];
    }
    __syncthreads();
#pragma unroll
    for (int i = 0; i < 4; ++i) {
      int rr = tr + i * 8;
      out[(size_t)(c0 + rr) * R + (r0 + tc)] = f2bf(tile[tc][rr]);
    }
  } else {
    int gid = (bid - 10240) * 256 + threadIdx.x;  // chunk of 8 elems
    int b = gid >> 9, c = gid & 511;              // 512 chunks per 4096-row
    const float* src;
    if (c < EMBD / 8) {
      int e = ballot[b] * 8 + contest[b];
      src = emb + (size_t)e * EMBD + c * 8;
    } else {
      src = inputs + (size_t)b * D_INN + (c - EMBD / 8) * 8;
    }
    float4 v0 = *(const float4*)src;
    float4 v1 = *(const float4*)(src + 4);
    unsigned short r[8];
    r[0] = f2bf(v0.x); r[1] = f2bf(v0.y); r[2] = f2bf(v0.z); r[3] = f2bf(v0.w);
    r[4] = f2bf(v1.x); r[5] = f2bf(v1.y); r[6] = f2bf(v1.z); r[7] = f2bf(v1.w);
    *reinterpret_cast<short8*>(A + (size_t)b * KDIM + c * 8) =
        *reinterpret_cast<const short8*>(r);
  }
}

// ---- GEMM1: 256x256 tile, 16 waves (1024 thr), ring-3, 1 barrier/tile ----
// (round-9 version, unchanged: best-measured GEMM1, 54-56% MfmaUtil)
template <int K>
__global__ __launch_bounds__(1024) void gemm_nt_16w(
    const unsigned short* __restrict__ A, const unsigned short* __restrict__ Bt,
    const float* __restrict__ bias, unsigned short* __restrict__ C,
    int N, int NBN) {
  constexpr int SLOT = 16384;                 // bytes per ring slot (256x32 bf16)
  __shared__ char lds[6 * SLOT];              // A slots 0..2, B slots 3..5 (96 KB)

  const int tid = threadIdx.x;
  const int w = tid >> 6, l = tid & 63;
  const int lr = l & 15, kg = l >> 4;
  const int wm = w >> 2, wn = w & 3;          // 4x4 wave grid

  int swz = (blockIdx.x & 7) * ((int)gridDim.x >> 3) + ((int)blockIdx.x >> 3);
  const int bm = swz / NBN, bn = swz - bm * NBN;
  const int NT = K >> 5;

  const int srow = tid >> 2;
  const int swzsl = (tid & 3) ^ ((srow >> 1) & 3);
  const unsigned short* gaB = A + (size_t)(bm * 256 + srow) * K + swzsl * 8;
  const unsigned short* gbB = Bt + (size_t)(bn * 256 + srow) * K + swzsl * 8;

  const int xo = (kg ^ ((lr >> 1) & 3)) << 4;
  const int aoff = (wm * 64 + lr) * 64 + xo;
  const int boff = (wn * 64 + lr) * 64 + xo;

  f32x4 acc[4][4] = {};

  auto stageA = [&](int t, int rbuf) {
    gld_lds16(gaB + t * 32, lds + rbuf * SLOT + tid * 16);
  };
  auto stageB = [&](int t, int rbuf) {
    gld_lds16(gbB + t * 32, lds + 3 * SLOT + rbuf * SLOT + tid * 16);
  };

  stageA(0, 0); stageB(0, 0);
  stageA(1, 1); stageB(1, 1);
  asm volatile("s_waitcnt vmcnt(2)" ::: "memory");
  __builtin_amdgcn_s_barrier();

  int rb = 0;
  for (int t = 0; t < NT; ++t) {
    int rb2 = rb + 2; if (rb2 >= 3) rb2 -= 3;
    const char* pa = lds + rb * SLOT + aoff;
    const char* pb = lds + 3 * SLOT + rb * SLOT + boff;

    short8 a0[2], bfr[4];
#pragma unroll
    for (int mi = 0; mi < 2; ++mi) a0[mi] = *(const short8*)(pa + mi * 1024);
#pragma unroll
    for (int ni = 0; ni < 4; ++ni) bfr[ni] = *(const short8*)(pb + ni * 1024);
    if (t + 2 < NT) stageA(t + 2, rb2);
    __builtin_amdgcn_s_setprio(1);
#pragma unroll
    for (int mi = 0; mi < 2; ++mi)
#pragma unroll
      for (int ni = 0; ni < 4; ++ni)
        acc[mi][ni] = MFMA_BF16(a0[mi], bfr[ni], acc[mi][ni], 0, 0, 0);
    __builtin_amdgcn_s_setprio(0);

    short8 a1[2];
#pragma unroll
    for (int mi = 0; mi < 2; ++mi) a1[mi] = *(const short8*)(pa + (2 + mi) * 1024);
    if (t + 2 < NT) stageB(t + 2, rb2);
    __builtin_amdgcn_s_setprio(1);
#pragma unroll
    for (int mi = 0; mi < 2; ++mi)
#pragma unroll
      for (int ni = 0; ni < 4; ++ni)
        acc[2 + mi][ni] = MFMA_BF16(a1[mi], bfr[ni], acc[2 + mi][ni], 0, 0, 0);
    __builtin_amdgcn_s_setprio(0);

    if (t + 2 < NT) {
      asm volatile("s_waitcnt vmcnt(2)" ::: "memory");
      __builtin_amdgcn_s_barrier();
    } else if (t + 1 < NT) {
      asm volatile("s_waitcnt vmcnt(0)" ::: "memory");
      __builtin_amdgcn_s_barrier();
    }
    rb = rb + 1; if (rb >= 3) rb = 0;
  }

#pragma unroll
  for (int mi = 0; mi < 4; ++mi) {
    const int row0 = bm * 256 + wm * 64 + mi * 16 + kg * 4;
#pragma unroll
    for (int ni = 0; ni < 4; ++ni) {
      const int col = bn * 256 + wn * 64 + ni * 16 + lr;
      const float bv = bias[col];
#pragma unroll
      for (int j = 0; j < 4; ++j) {
        float v = acc[mi][ni][j] + bv;
        v = v > 0.f ? v : 0.f;
        C[(size_t)(row0 + j) * N + col] = f2bf(v);
      }
    }
  }
}

// ---- GEMM2 + We-transpose in ONE launch (grid 320, 512 thr) ----
// blocks [0,64): transpose We[e][1024][32] f32 -> Wet[e][32][1024] bf16
//   (runs ~2 us, vacates CUs for the trailing GEMM blocks)
// blocks [64,320): GEMM2 128x256 tile, 8 waves, wave 64x64, BK=32 ring-3
//   (round-11 verified body; swizzle re-based on bid-64 over 256 blocks)
__global__ __launch_bounds__(512) void gemm2_plus_we(
    const unsigned short* __restrict__ A, const unsigned short* __restrict__ Bt,
    const float* __restrict__ bias, unsigned short* __restrict__ C,
    const float* __restrict__ We, unsigned short* __restrict__ Wet) {
  constexpr int K = H0D, N = H1D, NBN = 4;
  constexpr int ASLOT = 8192, BSLOT = 16384;
  constexpr int NT = K >> 5;                   // 64
  __shared__ char lds[3 * (ASLOT + BSLOT)];    // 73728 B

  if (blockIdx.x < 64) {
    // ---- We transpose: expert e, 512 threads = 2 sub-tiles in flight ----
    const int e = blockIdx.x;
    const float* src = We + (size_t)e * 32768;
    unsigned short* dst = Wet + (size_t)e * 32768;
    float* tl = (float*)lds + (threadIdx.x >> 8) * (32 * 33);  // 2 x 32x33 tiles
    const int t = threadIdx.x & 255;
    const int tc = t & 31, tr = t >> 5;        // tr 0..7
    const int sub = threadIdx.x >> 8;          // 0/1
    for (int it = 0; it < 16; ++it) {
      const int r0 = (it * 2 + sub) * 32;
      __syncthreads();                          // protect prev iter's readers
#pragma unroll
      for (int i = 0; i < 4; ++i) {
        int r = tr + i * 8;
        tl[r * 33 + tc] = src[(size_t)(r0 + r) * 32 + tc];
      }
      __syncthreads();
#pragma unroll
      for (int i = 0; i < 4; ++i) {
        int rr = tr + i * 8;
        dst[(size_t)rr * H1D + r0 + tc] = f2bf(tl[tc * 33 + rr]);
      }
    }
    return;
  }

  const int bid = blockIdx.x - 64;             // 0..255
  const int tid = threadIdx.x;
  const int w = tid >> 6, l = tid & 63;
  const int lr = l & 15, kg = l >> 4;
  const int wm = w >> 2, wn = w & 3;

  int swz = (bid & 7) * 32 + (bid >> 3);       // 256-block bijective XCD swizzle
  const int bm = swz / NBN, bn = swz - bm * NBN;

  const int srow = tid >> 2;                   // 0..127
  const int swzsl = (tid & 3) ^ ((srow >> 1) & 3);
  const unsigned short* gaB = A + (size_t)(bm * 128 + srow) * K + swzsl * 8;
  const unsigned short* gb0 = Bt + (size_t)(bn * 256 + srow) * K + swzsl * 8;
  const unsigned short* gb1 = gb0 + (size_t)128 * K;

  const int xo = (kg ^ ((lr >> 1) & 3)) << 4;
  const int aoff = (wm * 64 + lr) * 64 + xo;   // + mi*1024 (rows 0..127)
  const int boff = (wn * 64 + lr) * 64 + xo;   // + ni*1024 (rows 0..255)

  f32x4 acc[4][4] = {};

  auto stage = [&](int t, int rbuf) {
    gld_lds16(gaB + t * 32, lds + rbuf * ASLOT + tid * 16);
    char* lb = lds + 3 * ASLOT + rbuf * BSLOT + tid * 16;
    gld_lds16(gb0 + t * 32, lb);
    gld_lds16(gb1 + t * 32, lb + 8192);
  };

  stage(0, 0);
  stage(1, 1);
  asm volatile("s_waitcnt vmcnt(3)" ::: "memory");   // tile 0 landed
  __builtin_amdgcn_s_barrier();

  int rb = 0;
  for (int t = 0; t < NT; ++t) {
    int rb2 = rb + 2; if (rb2 >= 3) rb2 -= 3;
    const char* pa = lds + rb * ASLOT + aoff;
    const char* pb = lds + 3 * ASLOT + rb * BSLOT + boff;

    short8 a[4], b[4];
#pragma unroll
    for (int mi = 0; mi < 4; ++mi) a[mi] = *(const short8*)(pa + mi * 1024);
#pragma unroll
    for (int ni = 0; ni < 4; ++ni) b[ni] = *(const short8*)(pb + ni * 1024);
    if (t + 2 < NT) stage(t + 2, rb2);
    __builtin_amdgcn_s_setprio(1);
#pragma unroll
    for (int mi = 0; mi < 4; ++mi)
#pragma unroll
      for (int ni = 0; ni < 4; ++ni)
        acc[mi][ni] = MFMA_BF16(a[mi], b[ni], acc[mi][ni], 0, 0, 0);
    __builtin_amdgcn_s_setprio(0);

    if (t + 2 < NT) {
      asm volatile("s_waitcnt vmcnt(3)" ::: "memory");  // t+1 landed
      __builtin_amdgcn_s_barrier();
    } else if (t + 1 < NT) {
      asm volatile("s_waitcnt vmcnt(0)" ::: "memory");
      __builtin_amdgcn_s_barrier();
    }
    rb = rb + 1; if (rb >= 3) rb = 0;
  }

#pragma unroll
  for (int mi = 0; mi < 4; ++mi) {
    const int row0 = bm * 128 + wm * 64 + mi * 16 + kg * 4;
#pragma unroll
    for (int ni = 0; ni < 4; ++ni) {
      const int col = bn * 256 + wn * 64 + ni * 16 + lr;
      const float bv = bias[col];
#pragma unroll
      for (int j = 0; j < 4; ++j) {
        float v = acc[mi][ni][j] + bv;
        v = v > 0.f ? v : 0.f;
        C[(size_t)(row0 + j) * N + col] = f2bf(v);
      }
    }
  }
}

// ---- routed expert head via MFMA: 128 blocks = expert x sample-half ----
__global__ __launch_bounds__(256) void expert_head_mfma(
    const unsigned short* __restrict__ h1, const unsigned short* __restrict__ Wet,
    const float* __restrict__ be, const int* __restrict__ ballot,
    const int* __restrict__ contest, float* __restrict__ out) {
  const int e = blockIdx.x >> 1, half = blockIdx.x & 1;
  __shared__ unsigned short sidx[1024];
  __shared__ int scnt;
  if (threadIdx.x == 0) scnt = 0;
  __syncthreads();
  const int lo = half * (B_SZ / 2), hi = lo + B_SZ / 2;
  for (int i = lo + threadIdx.x; i < hi; i += 256)
    if (ballot[i] * 8 + contest[i] == e) {
      int p = atomicAdd(&scnt, 1);
      if (p < 1024) sidx[p] = (unsigned short)i;
    }
  __syncthreads();
  const int cnt = min(scnt, 1024);
  const int w = threadIdx.x >> 6, l = threadIdx.x & 63;
  const int lr = l & 15, kg = l >> 4;
  const unsigned short* wbase = Wet + (size_t)e * 32768;
  for (int c0 = w * 32; c0 < cnt; c0 += 128) {
    const int ns = min(32, cnt - c0);
    f32x4 acc[2][2] = {};
    int ridx[2];
#pragma unroll
    for (int mi = 0; mi < 2; ++mi) {
      int rr = mi * 16 + lr;
      ridx[mi] = sidx[c0 + (rr < ns ? rr : 0)];
    }
#pragma unroll 4
    for (int kk = 0; kk < 32; ++kk) {
      short8 a0 = *(const short8*)(h1 + (size_t)ridx[0] * H1D + kk * 32 + kg * 8);
      short8 a1 = *(const short8*)(h1 + (size_t)ridx[1] * H1D + kk * 32 + kg * 8);
      short8 b0 = *(const short8*)(wbase + (size_t)lr * H1D + kk * 32 + kg * 8);
      short8 b1 = *(const short8*)(wbase + (size_t)(16 + lr) * H1D + kk * 32 + kg * 8);
      acc[0][0] = MFMA_BF16(a0, b0, acc[0][0], 0, 0, 0);
      acc[0][1] = MFMA_BF16(a0, b1, acc[0][1], 0, 0, 0);
      acc[1][0] = MFMA_BF16(a1, b0, acc[1][0], 0, 0, 0);
      acc[1][1] = MFMA_BF16(a1, b1, acc[1][1], 0, 0, 0);
    }
#pragma unroll
    for (int mi = 0; mi < 2; ++mi)
#pragma unroll
      for (int ni = 0; ni < 2; ++ni)
#pragma unroll
        for (int j = 0; j < 4; ++j) {
          int row = mi * 16 + kg * 4 + j;
          int col = ni * 16 + lr;
          if (row < ns) {
            float x = acc[mi][ni][j] + be[e * 32 + col];
            out[(size_t)sidx[c0 + row] * 32 + col] = 1.f / (1.f + expf(-x));
          }
        }
  }
}

extern "C" void kernel_launch(void* const* d_in, const int* in_sizes, int n_in,
                              void* d_out, int out_size, void* d_ws, size_t ws_size,
                              hipStream_t stream) {
  const float* inputs = (const float*)d_in[0];
  const float* emb    = (const float*)d_in[1];
  const float* W0     = (const float*)d_in[2];
  const float* b0     = (const float*)d_in[3];
  const float* W1     = (const float*)d_in[4];
  const float* b1     = (const float*)d_in[5];
  const float* We     = (const float*)d_in[6];
  const float* be     = (const float*)d_in[7];
  const int* ballot   = (const int*)d_in[8];
  const int* contest  = (const int*)d_in[9];
  float* out = (float*)d_out;

  char* ws = (char*)d_ws;
  unsigned short* A   = (unsigned short*)(ws);                 //  67108864 B
  unsigned short* W0t = (unsigned short*)(ws + 67108864);      //  16777216 B
  unsigned short* h0  = (unsigned short*)(ws + 83886080);      //  33554432 B
  unsigned short* W1t = (unsigned short*)(ws + 117440512);     //   4194304 B
  unsigned short* h1  = (unsigned short*)(ws + 121634816);     //  16777216 B
  unsigned short* Wet = (unsigned short*)(ws);                 // aliases A (dead after GEMM1)

  // prep: W0t + W1t transposes AND build_A, one launch (26624 blocks)
  prep_inputs<<<dim3(26624), dim3(256), 0, stream>>>(
      W0, W1, W0t, W1t, inputs, emb, ballot, contest, A);
  // GEMM1: 256x256 tiles -> 256 blocks, 16-wave ring-3, 1 barrier/tile
  gemm_nt_16w<KDIM><<<dim3(256), dim3(1024), 0, stream>>>(A, W0t, b0, h0, H0D, H0D / 256);
  // GEMM2 (256 blocks) + We transpose (64 blocks) in one launch
  gemm2_plus_we<<<dim3(320), dim3(512), 0, stream>>>(h0, W1t, b1, h1, We, Wet);
  // routed head: 128 blocks (expert x sample-half), MFMA matvec
  expert_head_mfma<<<dim3(128), dim3(256), 0, stream>>>(h1, Wet, be, ballot, contest, out);
}